// Round 14
// baseline (595.978 us; speedup 1.0000x reference)
//
#include <hip/hip_runtime.h>
#include <hip/hip_bf16.h>

typedef unsigned short u16;
typedef unsigned int u32;
typedef __attribute__((ext_vector_type(8))) short bf16x8;     // MFMA A/B frag (8 bf16)
typedef __attribute__((ext_vector_type(8))) unsigned short us8;
typedef __attribute__((ext_vector_type(4))) float f32x4;      // MFMA C/D frag

// ---------------------------------------------------------------------------
// Pipeline (v10 = r11-verified base + issue-early/proc-late A-gen + exp2 gate):
//   node GEMMs -> Hs,Hd,Gs,Gd,Bd (bf16, 72MB); Gs,Gd pre-scaled by -log2e
//   counting-sort edges by d (sd=int2 pairs, pe=orig index)
//   z1 = (sigmoid * [Hs[s],Hd[d]]) @ W1.T + stats + fused bilinear
//   z2 = relu(bn(z1)) @ W2.T  in-place + stats
//   out[pe[i]] = dot(relu(bn(z2[i])),W3) + b3 + bil[i]
// Edge GEMM: 64x256 tile, BK=64, 4 waves of 64x64; B via global_load_lds
// from pre-swizzled slab-major weights. NEW: per slab the order is
// rawLoad(ks+1) [issue gathers] -> mfma_slab(ks) [covers latency] ->
// proc(ks+1) [gate VALU on arrived data] -> barrier -> writeA -> gloadB.
// K-loop fully unrolled (template NKS) so all reg indices are static.
// ---------------------------------------------------------------------------

__device__ __forceinline__ float b2f(u16 u) {
    union { unsigned u32v; float f; } x; x.u32v = ((unsigned)u) << 16; return x.f;
}
__device__ __forceinline__ u16 f2b(float f) {
    __hip_bfloat16 h = __float2bfloat16(f);
    u16 r; __builtin_memcpy(&r, &h, 2); return r;
}

struct CvtSeg { const float* in; u16* out; int n4; };
struct CvtArr { CvtSeg s[4]; int tot4; };
__global__ __launch_bounds__(256) void cvt_fused(CvtArr ca) {
    int i = blockIdx.x * 256 + threadIdx.x;
    if (i >= ca.tot4) return;
    int k = 0, off = i;
#pragma unroll
    for (int q = 0; q < 4; ++q) {
        if (off < ca.s[q].n4) { k = q; break; }
        off -= ca.s[q].n4;
    }
    float4 v = ((const float4*)ca.s[k].in)[off];
    ushort4 o; o.x = f2b(v.x); o.y = f2b(v.y); o.z = f2b(v.z); o.w = f2b(v.w);
    ((ushort4*)ca.s[k].out)[off] = o;
}

// repack W [256][K] f32 -> slab-major swizzled bf16 [K/64][256][64]
__global__ __launch_bounds__(256) void repack_swz(const float* __restrict__ W,
                                                  u16* __restrict__ out,
                                                  int total, int kbits) {
    int idx = blockIdx.x * 256 + threadIdx.x;
    if (idx >= total) return;
    const int n = idx >> kbits;
    const int k = idx & ((1 << kbits) - 1);
    const int ks = k >> 6, ke = k & 63;
    const int j = ke ^ ((n & 7) << 3);
    out[(((ks << 8) + n) << 6) + j] = f2b(W[idx]);
}

// ------------------------- edge sort by dst ---------------------------------
__global__ __launch_bounds__(256) void hist_kernel(const int* __restrict__ ei,
                                                   int E, u32* __restrict__ hist) {
    int e = blockIdx.x * 256 + threadIdx.x;
    if (e < E) atomicAdd(&hist[ei[E + e]], 1u);
}

__global__ __launch_bounds__(256) void scan_kernel(const u32* __restrict__ hist,
                                                   u32* __restrict__ cursor, int n) {
    __shared__ u32 part[256];
    const int t = threadIdx.x;
    const int chunk = (n + 255) / 256;
    const int lo = t * chunk, hi = min(lo + chunk, n);
    u32 s = 0;
    for (int i = lo; i < hi; ++i) s += hist[i];
    part[t] = s;
    __syncthreads();
    for (int off = 1; off < 256; off <<= 1) {
        u32 v = (t >= off) ? part[t - off] : 0u;
        __syncthreads();
        part[t] += v;
        __syncthreads();
    }
    u32 base = (t == 0) ? 0u : part[t - 1];
    for (int i = lo; i < hi; ++i) {
        cursor[i] = base;
        base += hist[i];
    }
}

__global__ __launch_bounds__(256) void scatter_kernel(const int* __restrict__ ei,
                                                      int E, u32* __restrict__ cursor,
                                                      int2* __restrict__ sd,
                                                      int* __restrict__ pe) {
    int e = blockIdx.x * 256 + threadIdx.x;
    if (e >= E) return;
    const int d = ei[E + e];
    const u32 pos = atomicAdd(&cursor[d], 1u);
    sd[pos] = make_int2(ei[e], d);
    pe[pos] = e;
}

// ------------------------- node GEMMs (desc-driven) -------------------------
struct GDesc {
    const void* A; int lda; int a_f32;
    const u16* W; int ldb;
    u16* C; int ldc;
    int K;
    const float* bias;
    float cscale;                    // C = (A@W.T + bias) * cscale
};
template <int NY> struct GDescArr { GDesc d[NY]; };

template <int NY>
__global__ __launch_bounds__(256, 2) void mfma_node(GDescArr<NY> da, int M)
{
    const GDesc dd = da.d[blockIdx.y];
    __shared__ u16 As[2][128][40];
    __shared__ u16 Bs[2][256][40];
    const int t = threadIdx.x;
    const int row0 = blockIdx.x * 128;
    const int arow = t >> 1, aks = (t & 1) * 16;
    const int agr = min(row0 + arow, M - 1);
    const int w = t >> 6, lane = t & 63;
    const int wr = w >> 1, wc = w & 1;
    const int lrow = lane & 15, lkg = lane >> 4;
    const int NIT = dd.K >> 5;

    f32x4 acc[4][8] = {};
    us8 ar[2], br[4];
    float4 fr[4];

    auto load_regs = [&](int it) {
        const int k0 = it << 5;
        if (dd.a_f32) {
            const float* ap = (const float*)dd.A + (size_t)agr * dd.lda + k0 + aks;
#pragma unroll
            for (int q = 0; q < 4; ++q) fr[q] = *(const float4*)(ap + q * 4);
        } else {
            const u16* ap = (const u16*)dd.A + (size_t)agr * dd.lda + k0 + aks;
            ar[0] = *(const us8*)ap; ar[1] = *(const us8*)(ap + 8);
        }
        const u16* wp = dd.W + (size_t)t * dd.ldb + k0;
#pragma unroll
        for (int q = 0; q < 4; ++q) br[q] = *(const us8*)(wp + q * 8);
    };
    auto proc_write = [&](int b) {
        if (dd.a_f32) {
#pragma unroll
            for (int q = 0; q < 2; ++q) {
                us8 o;
                const float fq[8] = {fr[q*2].x, fr[q*2].y, fr[q*2].z, fr[q*2].w,
                                     fr[q*2+1].x, fr[q*2+1].y, fr[q*2+1].z, fr[q*2+1].w};
#pragma unroll
                for (int j = 0; j < 8; ++j) o[j] = f2b(fq[j]);
                *(us8*)&As[b][arow][aks + q * 8] = o;
            }
        } else {
            *(us8*)&As[b][arow][aks] = ar[0];
            *(us8*)&As[b][arow][aks + 8] = ar[1];
        }
#pragma unroll
        for (int q = 0; q < 4; ++q) *(us8*)&Bs[b][t][q * 8] = br[q];
    };
    auto do_mfma = [&](int b) {
        bf16x8 af[4];
#pragma unroll
        for (int mi = 0; mi < 4; ++mi)
            af[mi] = *(const bf16x8*)&As[b][wr * 64 + mi * 16 + lrow][lkg * 8];
#pragma unroll
        for (int ni = 0; ni < 8; ++ni) {
            bf16x8 bfr = *(const bf16x8*)&Bs[b][wc * 128 + ni * 16 + lrow][lkg * 8];
#pragma unroll
            for (int mi = 0; mi < 4; ++mi)
                acc[mi][ni] = __builtin_amdgcn_mfma_f32_16x16x32_bf16(
                    af[mi], bfr, acc[mi][ni], 0, 0, 0);
        }
    };

    load_regs(0); proc_write(0); __syncthreads();
    for (int it = 0; it < NIT; ++it) {
        const int cur = it & 1;
        if (it + 1 < NIT) load_regs(it + 1);
        do_mfma(cur);
        if (it + 1 < NIT) proc_write(cur ^ 1);
        __syncthreads();
    }

#pragma unroll
    for (int ni = 0; ni < 8; ++ni) {
        const int gcol = wc * 128 + ni * 16 + lrow;
        const float bv = dd.bias ? dd.bias[gcol] : 0.f;
#pragma unroll
        for (int mi = 0; mi < 4; ++mi) {
            f32x4 v = acc[mi][ni];
#pragma unroll
            for (int j = 0; j < 4; ++j) {
                const int grow = row0 + wr * 64 + mi * 16 + lkg * 4 + j;
                if (grow < M)
                    dd.C[(size_t)grow * dd.ldc + gcol] = f2b((v[j] + bv) * dd.cscale);
            }
        }
    }
}

// ------------------------- edge GEMMs (z1 / z2) -----------------------------
#define OP_GATE   1
#define OP_BNRELU 2

template <int AOP, int NKS>
__global__ __launch_bounds__(256) void mfma_edge(
    const u16* __restrict__ Ain,            // z (BNRELU)
    const u16* __restrict__ Wb,             // slab-major swizzled [NKS][256][64]
    u16* __restrict__ C, int E,
    const int2* __restrict__ sd,            // sorted (s,d) pairs
    const u16* __restrict__ Gs, const u16* __restrict__ Gd,
    const u16* __restrict__ Hs, const u16* __restrict__ Hd,
    const u16* __restrict__ Bd, const float* __restrict__ b_bil,
    float* __restrict__ bil,
    const float* __restrict__ scaleK, const float* __restrict__ shiftK,
    float* __restrict__ sums)
{
    __shared__ u16 As[64][72];        // padded: <=2-way banks on ds_read
    __shared__ u16 Bs[256 * 64];      // LINEAR (gload_lds dest), swizzled content
    __shared__ float wsum[2][256];

    const int t = threadIdx.x;
    const int row0 = blockIdx.x * 64;
    const int arow = t >> 2;          // 0..63 staged row (4 thr/row)
    const int aks  = (t & 3) * 16;    // k-offset within 64-slab
    const int agr = min(row0 + arow, E - 1);

    int s_ = 0, d_ = 0;
    if constexpr (AOP == OP_GATE) {
        int2 p = sd[agr]; s_ = p.x; d_ = p.y;
    }

    const int lane = t & 63;
    const int w = t >> 6;             // wave -> cols [w*64, w*64+64)
    const int lrow = lane & 15, lkg = lane >> 4;

    f32x4 acc[4][4] = {};
    float bdot = 0.f;
    us8 aw0, aw1;                     // processed A (written to LDS)
    us8 r0, r1, r2, r3, r4, r5, r6, r7;   // raw gather regs
    float4 c0, c1, c2, c3, h0, h1, h2, h3; // BNRELU scale/shift regs

    // issue-only: global loads for slab ks (no dependent VALU here)
    auto rawLoad = [&](int ks) {
        const int k = ks * 64 + aks;
        if constexpr (AOP == OP_GATE) {
            r0 = *(const us8*)(Gs + (size_t)s_ * 512 + k);
            r1 = *(const us8*)(Gs + (size_t)s_ * 512 + k + 8);
            r2 = *(const us8*)(Gd + (size_t)d_ * 512 + k);
            r3 = *(const us8*)(Gd + (size_t)d_ * 512 + k + 8);
            const u16* hp = (ks < 4) ? (Hs + (size_t)s_ * 256 + k)
                                     : (Hd + (size_t)d_ * 256 + k - 256);
            r4 = *(const us8*)hp; r5 = *(const us8*)(hp + 8);
            if (ks < 4) {
                r6 = *(const us8*)(Bd + (size_t)d_ * 256 + k);
                r7 = *(const us8*)(Bd + (size_t)d_ * 256 + k + 8);
            }
        } else {
            r0 = *(const us8*)(Ain + (size_t)agr * 256 + k);
            r1 = *(const us8*)(Ain + (size_t)agr * 256 + k + 8);
            c0 = *(const float4*)(scaleK + k);
            c1 = *(const float4*)(scaleK + k + 4);
            c2 = *(const float4*)(scaleK + k + 8);
            c3 = *(const float4*)(scaleK + k + 12);
            h0 = *(const float4*)(shiftK + k);
            h1 = *(const float4*)(shiftK + k + 4);
            h2 = *(const float4*)(shiftK + k + 8);
            h3 = *(const float4*)(shiftK + k + 12);
        }
    };
    // VALU on arrived data -> aw0/aw1 (+bilinear for GATE, ks<4)
    auto proc = [&](int ks) {
        if constexpr (AOP == OP_GATE) {
#pragma unroll
            for (int j = 0; j < 8; ++j) {
                // Gs,Gd pre-scaled by -log2e: sigmoid = rcp(1 + 2^(gs+gd))
                const float x0 = b2f(r0[j]) + b2f(r2[j]);
                const float x1 = b2f(r1[j]) + b2f(r3[j]);
                const float g0 = __builtin_amdgcn_rcpf(1.f + __builtin_amdgcn_exp2f(x0));
                const float g1 = __builtin_amdgcn_rcpf(1.f + __builtin_amdgcn_exp2f(x1));
                aw0[j] = f2b(b2f(r4[j]) * g0);
                aw1[j] = f2b(b2f(r5[j]) * g1);
            }
            if (ks < 4) {
#pragma unroll
                for (int j = 0; j < 8; ++j) {
                    bdot = fmaf(b2f(r4[j]), b2f(r6[j]), bdot);
                    bdot = fmaf(b2f(r5[j]), b2f(r7[j]), bdot);
                }
            }
        } else {
            const float scq[16] = {c0.x,c0.y,c0.z,c0.w, c1.x,c1.y,c1.z,c1.w,
                                   c2.x,c2.y,c2.z,c2.w, c3.x,c3.y,c3.z,c3.w};
            const float shq[16] = {h0.x,h0.y,h0.z,h0.w, h1.x,h1.y,h1.z,h1.w,
                                   h2.x,h2.y,h2.z,h2.w, h3.x,h3.y,h3.z,h3.w};
#pragma unroll
            for (int j = 0; j < 8; ++j) {
                aw0[j] = f2b(fmaxf(fmaf(b2f(r0[j]), scq[j],     shq[j]),     0.f));
                aw1[j] = f2b(fmaxf(fmaf(b2f(r1[j]), scq[8 + j], shq[8 + j]), 0.f));
            }
        }
    };
    auto writeA = [&]() {
        *(us8*)&As[arow][aks]     = aw0;
        *(us8*)&As[arow][aks + 8] = aw1;
    };
    auto gloadB = [&](int ks) {
        const char* g = (const char*)(Wb + ((size_t)ks << 14)) + w * 8192 + lane * 16;
        char* l = (char*)Bs + w * 8192;
#pragma unroll
        for (int q = 0; q < 8; ++q)
            __builtin_amdgcn_global_load_lds(
                (const __attribute__((address_space(1))) unsigned int*)(g + q * 1024),
                (__attribute__((address_space(3))) unsigned int*)(l + q * 1024),
                16, 0, 0);
    };
    auto mfma_slab = [&]() {
#pragma unroll
        for (int kk = 0; kk < 64; kk += 32) {
            bf16x8 af[4], bf[4];
#pragma unroll
            for (int mi = 0; mi < 4; ++mi)
                af[mi] = *(const bf16x8*)&As[mi * 16 + lrow][kk + lkg * 8];
#pragma unroll
            for (int ni = 0; ni < 4; ++ni) {
                const int r = w * 64 + ni * 16 + lrow;
                bf[ni] = *(const bf16x8*)&Bs[r * 64 + ((kk + lkg * 8) ^ ((r & 7) << 3))];
            }
#pragma unroll
            for (int ni = 0; ni < 4; ++ni)
#pragma unroll
                for (int mi = 0; mi < 4; ++mi)
                    acc[mi][ni] = __builtin_amdgcn_mfma_f32_16x16x32_bf16(
                        af[mi], bf[ni], acc[mi][ni], 0, 0, 0);
        }
    };

    // prologue: slab 0 fully staged
    rawLoad(0); gloadB(0);
    proc(0); writeA();
    __syncthreads();                  // As0 visible + B0 DMA drained
#pragma unroll
    for (int ks = 0; ks < NKS; ++ks) {
        if (ks + 1 < NKS) rawLoad(ks + 1);   // issue gathers early
        mfma_slab();                         // covers gather latency
        if (ks + 1 < NKS) {
            proc(ks + 1);                    // gate VALU on arrived data
            __syncthreads();                 // As,Bs consumed by all waves
            writeA();
            gloadB(ks + 1);
            __syncthreads();                 // As(ks+1) visible + B drained
        }
    }

    if constexpr (AOP == OP_GATE) {
        bdot += __shfl_xor(bdot, 1, 64);
        bdot += __shfl_xor(bdot, 2, 64);
        if ((t & 3) == 0 && row0 + arow < E)
            bil[row0 + arow] = bdot + b_bil[0];
    }

    // epilogue: C-write + fused per-column stats
#pragma unroll
    for (int ni = 0; ni < 4; ++ni) {
        const int gcol = w * 64 + ni * 16 + lrow;
        float s = 0.f, ss = 0.f;
#pragma unroll
        for (int mi = 0; mi < 4; ++mi) {
            f32x4 v = acc[mi][ni];
#pragma unroll
            for (int j = 0; j < 4; ++j) {
                const int grow = row0 + mi * 16 + lkg * 4 + j;
                const float x = v[j];
                if (grow < E) {
                    C[(size_t)grow * 256 + gcol] = f2b(x);
                    s += x; ss = fmaf(x, x, ss);
                }
            }
        }
        s  += __shfl_xor(s, 16, 64);  s  += __shfl_xor(s, 32, 64);
        ss += __shfl_xor(ss, 16, 64); ss += __shfl_xor(ss, 32, 64);
        if (lkg == 0) { wsum[0][gcol] = s; wsum[1][gcol] = ss; }
    }
    __syncthreads();
    atomicAdd(&sums[t],       wsum[0][t]);
    atomicAdd(&sums[256 + t], wsum[1][t]);
}

__global__ void finalize_kernel(
    const float* __restrict__ sums, const float* __restrict__ g,
    const float* __restrict__ be, int M,
    float* __restrict__ scale, float* __restrict__ shift)
{
    const int c = threadIdx.x;
    const float inv = 1.f / (float)M;
    const float mean = sums[c] * inv;
    const float var  = sums[256 + c] * inv - mean * mean;
    const float sc = g[c] * rsqrtf(var + 1e-5f);
    scale[c] = sc;
    shift[c] = fmaf(-mean, sc, be[c]);
}

// out[pe[i]] = dot(relu(bn(z2[i])),W3)+b3 + bil[i]   (one wave / sorted edge)
__global__ __launch_bounds__(256) void final_kernel(
    const u16* __restrict__ Z2,
    const float* __restrict__ scale2, const float* __restrict__ shift2,
    const float* __restrict__ W3, const float* __restrict__ b3,
    const float* __restrict__ bil, const int* __restrict__ pe,
    float* __restrict__ out, int E)
{
    const int w = threadIdx.x >> 6, lane = threadIdx.x & 63;
    const int e = blockIdx.x * 4 + w;
    if (e >= E) return;
    ushort4 zv = *(const ushort4*)(Z2 + (size_t)e * 256 + lane * 4);
    float4 sc = *(const float4*)(scale2 + lane * 4);
    float4 sh = *(const float4*)(shift2 + lane * 4);
    float4 w3 = *(const float4*)(W3 + lane * 4);
    const u16 zq[4] = {zv.x, zv.y, zv.z, zv.w};
    const float scq[4] = {sc.x, sc.y, sc.z, sc.w};
    const float shq[4] = {sh.x, sh.y, sh.z, sh.w};
    const float wq[4] = {w3.x, w3.y, w3.z, w3.w};
    float acc = 0.f;
#pragma unroll
    for (int i = 0; i < 4; ++i) {
        const float x = fmaxf(fmaf(b2f(zq[i]), scq[i], shq[i]), 0.f);
        acc = fmaf(x, wq[i], acc);
    }
#pragma unroll
    for (int off = 32; off; off >>= 1) acc += __shfl_down(acc, off, 64);
    if (lane == 0) out[pe[e]] = acc + b3[0] + bil[e];
}

extern "C" void kernel_launch(void* const* d_in, const int* in_sizes, int n_in,
                              void* d_out, int out_size, void* d_ws, size_t ws_size,
                              hipStream_t stream)
{
    const float* x_drug = (const float*)d_in[0];
    const float* x_prot = (const float*)d_in[1];
    const int*   ei     = (const int*)d_in[2];
    const float* W_src  = (const float*)d_in[3];
    const float* W_dst  = (const float*)d_in[4];
    const float* W_gate = (const float*)d_in[5];
    const float* b_gate = (const float*)d_in[6];
    const float* W1     = (const float*)d_in[7];
    const float* g1     = (const float*)d_in[9];
    const float* be1    = (const float*)d_in[10];
    const float* W2     = (const float*)d_in[11];
    const float* g2     = (const float*)d_in[13];
    const float* be2    = (const float*)d_in[14];
    const float* W3     = (const float*)d_in[15];
    const float* b3     = (const float*)d_in[16];
    const float* W_bil  = (const float*)d_in[17];
    const float* b_bil  = (const float*)d_in[18];
    float* out = (float*)d_out;

    const int N = in_sizes[0] / 256;   // 20000
    const int E = in_sizes[2] / 2;     // 300000
    const float NL2E = -1.4426950408889634f;   // -log2(e)

    char* wp_ = (char*)d_ws;
    auto alloc = [&](size_t bytes) {
        char* p = wp_; wp_ += (bytes + 255) & ~(size_t)255; return p;
    };
    u16* Wsrcb  = (u16*)alloc(256 * 256 * 2);
    u16* Wdstb  = (u16*)alloc(256 * 512 * 2);
    u16* Wgateb = (u16*)alloc(512 * 512 * 2);
    u16* Wbilb  = (u16*)alloc(256 * 256 * 2);
    u16* W1s    = (u16*)alloc(256 * 512 * 2);   // slab-major swizzled
    u16* W2s    = (u16*)alloc(256 * 256 * 2);   // slab-major swizzled
    u16* Hs     = (u16*)alloc((size_t)N * 256 * 2);
    u16* Hd     = (u16*)alloc((size_t)N * 256 * 2);
    u16* Gs     = (u16*)alloc((size_t)N * 512 * 2);
    u16* Gd     = (u16*)alloc((size_t)N * 512 * 2);
    u16* Bd     = (u16*)alloc((size_t)N * 256 * 2);
    u16* z      = (u16*)alloc((size_t)E * 256 * 2);   // z1, then z2 in-place
    float* bil  = (float*)alloc((size_t)E * 4);
    u32*  hist  = (u32*)alloc((size_t)N * 4);
    u32*  cursor= (u32*)alloc((size_t)N * 4);
    int2* sd    = (int2*)alloc((size_t)E * 8);
    int*  pe    = (int*)alloc((size_t)E * 4);
    float* sums   = (float*)alloc(1024 * 4);
    float* scale1 = (float*)alloc(256 * 4);
    float* shift1 = (float*)alloc(256 * 4);
    float* scale2 = (float*)alloc(256 * 4);
    float* shift2 = (float*)alloc(256 * 4);

    hipMemsetAsync(sums, 0, 1024 * 4, stream);
    hipMemsetAsync(hist, 0, (size_t)N * 4, stream);

    // edge sort by d
    hist_kernel<<<(E + 255) / 256, 256, 0, stream>>>(ei, E, hist);
    scan_kernel<<<1, 256, 0, stream>>>(hist, cursor, N);
    scatter_kernel<<<(E + 255) / 256, 256, 0, stream>>>(ei, E, cursor, sd, pe);

    CvtArr ca;
    ca.s[0] = {W_src,  Wsrcb,  256 * 256 / 4};
    ca.s[1] = {W_dst,  Wdstb,  256 * 512 / 4};
    ca.s[2] = {W_gate, Wgateb, 512 * 512 / 4};
    ca.s[3] = {W_bil,  Wbilb,  256 * 256 / 4};
    ca.tot4 = 0;
    for (int q = 0; q < 4; ++q) ca.tot4 += ca.s[q].n4;
    cvt_fused<<<(ca.tot4 + 255) / 256, 256, 0, stream>>>(ca);

    repack_swz<<<(256 * 512 + 255) / 256, 256, 0, stream>>>(W1, W1s, 256 * 512, 9);
    repack_swz<<<(256 * 256 + 255) / 256, 256, 0, stream>>>(W2, W2s, 256 * 256, 8);

    const int gxN = (N + 127) / 128;   // 157
    const int gxE = (E + 63) / 64;     // 4688

    GDescArr<2> p1;
    p1.d[0] = {x_drug, 256, 1, Wsrcb, 256, Hs, 256, 256, nullptr, 1.f};
    p1.d[1] = {x_prot, 512, 1, Wdstb, 512, Hd, 256, 512, nullptr, 1.f};
    mfma_node<2><<<dim3(gxN, 2), 256, 0, stream>>>(p1, N);

    GDescArr<5> p2;
    p2.d[0] = {Hs, 256, 0, Wgateb,                 512, Gs,       512, 256, b_gate,       NL2E};
    p2.d[1] = {Hs, 256, 0, Wgateb + 256 * 512,     512, Gs + 256, 512, 256, b_gate + 256, NL2E};
    p2.d[2] = {Hd, 256, 0, Wgateb + 256,           512, Gd,       512, 256, nullptr,      NL2E};
    p2.d[3] = {Hd, 256, 0, Wgateb + 256 * 512 + 256, 512, Gd + 256, 512, 256, nullptr,    NL2E};
    p2.d[4] = {Hd, 256, 0, Wbilb,                  256, Bd,       256, 256, nullptr,      1.f};
    mfma_node<5><<<dim3(gxN, 5), 256, 0, stream>>>(p2, N);

    // z1 = gated h @ W1.T + stats1 + fused bilinear (sorted edge order)
    mfma_edge<OP_GATE, 8><<<gxE, 256, 0, stream>>>(
        nullptr, W1s, z, E,
        sd, Gs, Gd, Hs, Hd, Bd, b_bil, bil, nullptr, nullptr, sums);
    finalize_kernel<<<1, 256, 0, stream>>>(sums, g1, be1, E, scale1, shift1);

    // z2 = relu(bn(z1)) @ W2.T  (in-place) + stats2
    mfma_edge<OP_BNRELU, 4><<<gxE, 256, 0, stream>>>(
        z, W2s, z, E,
        nullptr, nullptr, nullptr, nullptr, nullptr, nullptr, nullptr, nullptr,
        scale1, shift1, sums + 512);
    finalize_kernel<<<1, 256, 0, stream>>>(sums + 512, g2, be2, E, scale2, shift2);

    final_kernel<<<(E + 3) / 4, 256, 0, stream>>>(
        z, scale2, shift2, W3, b3, bil, pe, out, E);
}

// Round 15
// 586.270 us; speedup vs baseline: 1.0166x; 1.0166x over previous
//
#include <hip/hip_runtime.h>
#include <hip/hip_bf16.h>

typedef unsigned short u16;
typedef unsigned int u32;
typedef __attribute__((ext_vector_type(8))) short bf16x8;     // MFMA A/B frag (8 bf16)
typedef __attribute__((ext_vector_type(8))) unsigned short us8;
typedef __attribute__((ext_vector_type(4))) float f32x4;      // MFMA C/D frag

// ---------------------------------------------------------------------------
// Pipeline (v11 = r11-verified base, edge GEMM re-decomposed for occupancy):
//   node GEMMs -> Hs,Hd,Gs,Gd,Bd (bf16, 72MB)
//   counting-sort edges by d (sd=int2 pairs, pe=orig index)
//   z1 = (sigmoid(Gs[s]+Gd[d]) * [Hs[s],Hd[d]]) @ W1.T + stats + fused bilinear
//   z2 = relu(bn(z1)) @ W2.T  in-place + stats
//   out[pe[i]] = dot(relu(bn(z2[i])),W3) + b3 + bil[i]
// Edge GEMM v11: 64x256 tile, BK=64, EIGHT waves each 64rows x 32cols
// (acc = 4x2 frags = 32 AGPR, was 64; raw gather regs halve too).
// Reg/wave ~100-110 -> 4-5 waves/SIMD; 2 blocks/CU x 8 waves = 16 waves/CU
// (was 12). Row dim NOT split across waves (r12's failed direction avoided).
// A staging: 8 thr/row x 8 k's. Loop/barriers/stats identical to r11.
// ---------------------------------------------------------------------------

__device__ __forceinline__ float b2f(u16 u) {
    union { unsigned u32v; float f; } x; x.u32v = ((unsigned)u) << 16; return x.f;
}
__device__ __forceinline__ u16 f2b(float f) {
    __hip_bfloat16 h = __float2bfloat16(f);
    u16 r; __builtin_memcpy(&r, &h, 2); return r;
}

struct CvtSeg { const float* in; u16* out; int n4; };
struct CvtArr { CvtSeg s[4]; int tot4; };
__global__ __launch_bounds__(256) void cvt_fused(CvtArr ca) {
    int i = blockIdx.x * 256 + threadIdx.x;
    if (i >= ca.tot4) return;
    int k = 0, off = i;
#pragma unroll
    for (int q = 0; q < 4; ++q) {
        if (off < ca.s[q].n4) { k = q; break; }
        off -= ca.s[q].n4;
    }
    float4 v = ((const float4*)ca.s[k].in)[off];
    ushort4 o; o.x = f2b(v.x); o.y = f2b(v.y); o.z = f2b(v.z); o.w = f2b(v.w);
    ((ushort4*)ca.s[k].out)[off] = o;
}

// repack W [256][K] f32 -> slab-major swizzled bf16 [K/64][256][64]
__global__ __launch_bounds__(256) void repack_swz(const float* __restrict__ W,
                                                  u16* __restrict__ out,
                                                  int total, int kbits) {
    int idx = blockIdx.x * 256 + threadIdx.x;
    if (idx >= total) return;
    const int n = idx >> kbits;
    const int k = idx & ((1 << kbits) - 1);
    const int ks = k >> 6, ke = k & 63;
    const int j = ke ^ ((n & 7) << 3);
    out[(((ks << 8) + n) << 6) + j] = f2b(W[idx]);
}

// ------------------------- edge sort by dst ---------------------------------
__global__ __launch_bounds__(256) void hist_kernel(const int* __restrict__ ei,
                                                   int E, u32* __restrict__ hist) {
    int e = blockIdx.x * 256 + threadIdx.x;
    if (e < E) atomicAdd(&hist[ei[E + e]], 1u);
}

__global__ __launch_bounds__(256) void scan_kernel(const u32* __restrict__ hist,
                                                   u32* __restrict__ cursor, int n) {
    __shared__ u32 part[256];
    const int t = threadIdx.x;
    const int chunk = (n + 255) / 256;
    const int lo = t * chunk, hi = min(lo + chunk, n);
    u32 s = 0;
    for (int i = lo; i < hi; ++i) s += hist[i];
    part[t] = s;
    __syncthreads();
    for (int off = 1; off < 256; off <<= 1) {
        u32 v = (t >= off) ? part[t - off] : 0u;
        __syncthreads();
        part[t] += v;
        __syncthreads();
    }
    u32 base = (t == 0) ? 0u : part[t - 1];
    for (int i = lo; i < hi; ++i) {
        cursor[i] = base;
        base += hist[i];
    }
}

__global__ __launch_bounds__(256) void scatter_kernel(const int* __restrict__ ei,
                                                      int E, u32* __restrict__ cursor,
                                                      int2* __restrict__ sd,
                                                      int* __restrict__ pe) {
    int e = blockIdx.x * 256 + threadIdx.x;
    if (e >= E) return;
    const int d = ei[E + e];
    const u32 pos = atomicAdd(&cursor[d], 1u);
    sd[pos] = make_int2(ei[e], d);
    pe[pos] = e;
}

// ------------------------- node GEMMs (desc-driven) -------------------------
struct GDesc {
    const void* A; int lda; int a_f32;
    const u16* W; int ldb;
    u16* C; int ldc;
    int K;
    const float* bias;
};
template <int NY> struct GDescArr { GDesc d[NY]; };

template <int NY>
__global__ __launch_bounds__(256, 2) void mfma_node(GDescArr<NY> da, int M)
{
    const GDesc dd = da.d[blockIdx.y];
    __shared__ u16 As[2][128][40];
    __shared__ u16 Bs[2][256][40];
    const int t = threadIdx.x;
    const int row0 = blockIdx.x * 128;
    const int arow = t >> 1, aks = (t & 1) * 16;
    const int agr = min(row0 + arow, M - 1);
    const int w = t >> 6, lane = t & 63;
    const int wr = w >> 1, wc = w & 1;
    const int lrow = lane & 15, lkg = lane >> 4;
    const int NIT = dd.K >> 5;

    f32x4 acc[4][8] = {};
    us8 ar[2], br[4];
    float4 fr[4];

    auto load_regs = [&](int it) {
        const int k0 = it << 5;
        if (dd.a_f32) {
            const float* ap = (const float*)dd.A + (size_t)agr * dd.lda + k0 + aks;
#pragma unroll
            for (int q = 0; q < 4; ++q) fr[q] = *(const float4*)(ap + q * 4);
        } else {
            const u16* ap = (const u16*)dd.A + (size_t)agr * dd.lda + k0 + aks;
            ar[0] = *(const us8*)ap; ar[1] = *(const us8*)(ap + 8);
        }
        const u16* wp = dd.W + (size_t)t * dd.ldb + k0;
#pragma unroll
        for (int q = 0; q < 4; ++q) br[q] = *(const us8*)(wp + q * 8);
    };
    auto proc_write = [&](int b) {
        if (dd.a_f32) {
#pragma unroll
            for (int q = 0; q < 2; ++q) {
                us8 o;
                const float fq[8] = {fr[q*2].x, fr[q*2].y, fr[q*2].z, fr[q*2].w,
                                     fr[q*2+1].x, fr[q*2+1].y, fr[q*2+1].z, fr[q*2+1].w};
#pragma unroll
                for (int j = 0; j < 8; ++j) o[j] = f2b(fq[j]);
                *(us8*)&As[b][arow][aks + q * 8] = o;
            }
        } else {
            *(us8*)&As[b][arow][aks] = ar[0];
            *(us8*)&As[b][arow][aks + 8] = ar[1];
        }
#pragma unroll
        for (int q = 0; q < 4; ++q) *(us8*)&Bs[b][t][q * 8] = br[q];
    };
    auto do_mfma = [&](int b) {
        bf16x8 af[4];
#pragma unroll
        for (int mi = 0; mi < 4; ++mi)
            af[mi] = *(const bf16x8*)&As[b][wr * 64 + mi * 16 + lrow][lkg * 8];
#pragma unroll
        for (int ni = 0; ni < 8; ++ni) {
            bf16x8 bfr = *(const bf16x8*)&Bs[b][wc * 128 + ni * 16 + lrow][lkg * 8];
#pragma unroll
            for (int mi = 0; mi < 4; ++mi)
                acc[mi][ni] = __builtin_amdgcn_mfma_f32_16x16x32_bf16(
                    af[mi], bfr, acc[mi][ni], 0, 0, 0);
        }
    };

    load_regs(0); proc_write(0); __syncthreads();
    for (int it = 0; it < NIT; ++it) {
        const int cur = it & 1;
        if (it + 1 < NIT) load_regs(it + 1);
        do_mfma(cur);
        if (it + 1 < NIT) proc_write(cur ^ 1);
        __syncthreads();
    }

#pragma unroll
    for (int ni = 0; ni < 8; ++ni) {
        const int gcol = wc * 128 + ni * 16 + lrow;
        const float bv = dd.bias ? dd.bias[gcol] : 0.f;
#pragma unroll
        for (int mi = 0; mi < 4; ++mi) {
            f32x4 v = acc[mi][ni];
#pragma unroll
            for (int j = 0; j < 4; ++j) {
                const int grow = row0 + wr * 64 + mi * 16 + lkg * 4 + j;
                if (grow < M) dd.C[(size_t)grow * dd.ldc + gcol] = f2b(v[j] + bv);
            }
        }
    }
}

// ------------------------- edge GEMMs (z1 / z2) -----------------------------
#define OP_GATE   1
#define OP_BNRELU 2

template <int AOP>
__global__ __launch_bounds__(512) void mfma_edge(
    const u16* __restrict__ Ain,            // z (BNRELU)
    const u16* __restrict__ Wb, int K,      // slab-major swizzled [K/64][256][64]
    u16* __restrict__ C, int E,
    const int2* __restrict__ sd,            // sorted (s,d) pairs
    const u16* __restrict__ Gs, const u16* __restrict__ Gd,
    const u16* __restrict__ Hs, const u16* __restrict__ Hd,
    const u16* __restrict__ Bd, const float* __restrict__ b_bil,
    float* __restrict__ bil,
    const float* __restrict__ scaleK, const float* __restrict__ shiftK,
    float* __restrict__ sums)
{
    __shared__ u16 As[64][72];        // padded: <=2-way banks on ds_read
    __shared__ u16 Bs[256 * 64];      // LINEAR (gload_lds dest), swizzled content
    __shared__ float wsum[2][256];

    const int t = threadIdx.x;        // 0..511
    const int row0 = blockIdx.x * 64;
    const int arow = t >> 3;          // 0..63 staged row (8 thr/row)
    const int aks  = (t & 7) * 8;     // k-offset within 64-slab
    const int agr = min(row0 + arow, E - 1);

    int s_ = 0, d_ = 0;
    if constexpr (AOP == OP_GATE) {
        int2 p = sd[agr]; s_ = p.x; d_ = p.y;
    }

    const int lane = t & 63;
    const int w = t >> 6;             // 0..7: wave -> cols [w*32, w*32+32)
    const int lrow = lane & 15, lkg = lane >> 4;
    const int NKS = K >> 6;

    f32x4 acc[4][2] = {};             // 32 AGPR (was 64)
    float bdot = 0.f;
    us8 aw0;                          // processed A (one us8/thread)
    us8 r0, r1, r2, r3;               // raw gather regs (one us8 per tensor)
    float4 c0, c1, h0, h1;            // BNRELU scale/shift regs

    auto loadA = [&](int ks) {
        const int k = ks * 64 + aks;
        if constexpr (AOP == OP_GATE) {
            r0 = *(const us8*)(Gs + (size_t)s_ * 512 + k);
            r1 = *(const us8*)(Gd + (size_t)d_ * 512 + k);
            const u16* hp = (ks < 4) ? (Hs + (size_t)s_ * 256 + k)
                                     : (Hd + (size_t)d_ * 256 + k - 256);
            r2 = *(const us8*)hp;
            if (ks < 4) r3 = *(const us8*)(Bd + (size_t)d_ * 256 + k);
        } else {
            r0 = *(const us8*)(Ain + (size_t)agr * 256 + k);
            c0 = *(const float4*)(scaleK + k);
            c1 = *(const float4*)(scaleK + k + 4);
            h0 = *(const float4*)(shiftK + k);
            h1 = *(const float4*)(shiftK + k + 4);
        }
    };
    auto proc = [&](int ks) {
        if constexpr (AOP == OP_GATE) {
#pragma unroll
            for (int j = 0; j < 8; ++j) {
                const float x = b2f(r0[j]) + b2f(r1[j]);
                const float g = __builtin_amdgcn_rcpf(1.f + __expf(-x));
                aw0[j] = f2b(b2f(r2[j]) * g);
            }
            if (ks < 4) {
#pragma unroll
                for (int j = 0; j < 8; ++j)
                    bdot = fmaf(b2f(r2[j]), b2f(r3[j]), bdot);
            }
        } else {
            const float scq[8] = {c0.x,c0.y,c0.z,c0.w, c1.x,c1.y,c1.z,c1.w};
            const float shq[8] = {h0.x,h0.y,h0.z,h0.w, h1.x,h1.y,h1.z,h1.w};
#pragma unroll
            for (int j = 0; j < 8; ++j)
                aw0[j] = f2b(fmaxf(fmaf(b2f(r0[j]), scq[j], shq[j]), 0.f));
        }
    };
    auto writeA = [&]() {
        *(us8*)&As[arow][aks] = aw0;
    };
    auto gloadB = [&](int ks) {
        // 8 waves x 4KB each: 4 calls x (64 lanes x 16B)
        const char* g = (const char*)(Wb + ((size_t)ks << 14)) + w * 4096 + lane * 16;
        char* l = (char*)Bs + w * 4096;
#pragma unroll
        for (int q = 0; q < 4; ++q)
            __builtin_amdgcn_global_load_lds(
                (const __attribute__((address_space(1))) unsigned int*)(g + q * 1024),
                (__attribute__((address_space(3))) unsigned int*)(l + q * 1024),
                16, 0, 0);
    };
    auto mfma_slab = [&]() {
#pragma unroll
        for (int kk = 0; kk < 64; kk += 32) {
            bf16x8 af[4], bf[2];
#pragma unroll
            for (int mi = 0; mi < 4; ++mi)
                af[mi] = *(const bf16x8*)&As[mi * 16 + lrow][kk + lkg * 8];
#pragma unroll
            for (int ni = 0; ni < 2; ++ni) {
                const int r = w * 32 + ni * 16 + lrow;
                bf[ni] = *(const bf16x8*)&Bs[r * 64 + ((kk + lkg * 8) ^ ((r & 7) << 3))];
            }
#pragma unroll
            for (int ni = 0; ni < 2; ++ni)
#pragma unroll
                for (int mi = 0; mi < 4; ++mi)
                    acc[mi][ni] = __builtin_amdgcn_mfma_f32_16x16x32_bf16(
                        af[mi], bf[ni], acc[mi][ni], 0, 0, 0);
        }
    };

    gloadB(0); loadA(0); proc(0);
    for (int ks = 0; ks < NKS; ++ks) {
        writeA();
        __syncthreads();                  // As visible + B DMA drained
        if (ks + 1 < NKS) { loadA(ks + 1); proc(ks + 1); }  // overlap MFMA
        mfma_slab();
        __syncthreads();                  // Bs fully consumed
        if (ks + 1 < NKS) gloadB(ks + 1); // next slab DMA in flight
    }

    if constexpr (AOP == OP_GATE) {
        bdot += __shfl_xor(bdot, 1, 64);
        bdot += __shfl_xor(bdot, 2, 64);
        bdot += __shfl_xor(bdot, 4, 64);
        if ((t & 7) == 0 && row0 + arow < E)
            bil[row0 + arow] = bdot + b_bil[0];
    }

    // epilogue: C-write + fused per-column stats
#pragma unroll
    for (int ni = 0; ni < 2; ++ni) {
        const int gcol = w * 32 + ni * 16 + lrow;
        float s = 0.f, ss = 0.f;
#pragma unroll
        for (int mi = 0; mi < 4; ++mi) {
            f32x4 v = acc[mi][ni];
#pragma unroll
            for (int j = 0; j < 4; ++j) {
                const int grow = row0 + mi * 16 + lkg * 4 + j;
                const float x = v[j];
                if (grow < E) {
                    C[(size_t)grow * 256 + gcol] = f2b(x);
                    s += x; ss = fmaf(x, x, ss);
                }
            }
        }
        s  += __shfl_xor(s, 16, 64);  s  += __shfl_xor(s, 32, 64);
        ss += __shfl_xor(ss, 16, 64); ss += __shfl_xor(ss, 32, 64);
        if (lkg == 0) { wsum[0][gcol] = s; wsum[1][gcol] = ss; }
    }
    __syncthreads();
    if (t < 256) {
        atomicAdd(&sums[t],       wsum[0][t]);
        atomicAdd(&sums[256 + t], wsum[1][t]);
    }
}

__global__ void finalize_kernel(
    const float* __restrict__ sums, const float* __restrict__ g,
    const float* __restrict__ be, int M,
    float* __restrict__ scale, float* __restrict__ shift)
{
    const int c = threadIdx.x;
    const float inv = 1.f / (float)M;
    const float mean = sums[c] * inv;
    const float var  = sums[256 + c] * inv - mean * mean;
    const float sc = g[c] * rsqrtf(var + 1e-5f);
    scale[c] = sc;
    shift[c] = fmaf(-mean, sc, be[c]);
}

// out[pe[i]] = dot(relu(bn(z2[i])),W3)+b3 + bil[i]   (one wave / sorted edge)
__global__ __launch_bounds__(256) void final_kernel(
    const u16* __restrict__ Z2,
    const float* __restrict__ scale2, const float* __restrict__ shift2,
    const float* __restrict__ W3, const float* __restrict__ b3,
    const float* __restrict__ bil, const int* __restrict__ pe,
    float* __restrict__ out, int E)
{
    const int w = threadIdx.x >> 6, lane = threadIdx.x & 63;
    const int e = blockIdx.x * 4 + w;
    if (e >= E) return;
    ushort4 zv = *(const ushort4*)(Z2 + (size_t)e * 256 + lane * 4);
    float4 sc = *(const float4*)(scale2 + lane * 4);
    float4 sh = *(const float4*)(shift2 + lane * 4);
    float4 w3 = *(const float4*)(W3 + lane * 4);
    const u16 zq[4] = {zv.x, zv.y, zv.z, zv.w};
    const float scq[4] = {sc.x, sc.y, sc.z, sc.w};
    const float shq[4] = {sh.x, sh.y, sh.z, sh.w};
    const float wq[4] = {w3.x, w3.y, w3.z, w3.w};
    float acc = 0.f;
#pragma unroll
    for (int i = 0; i < 4; ++i) {
        const float x = fmaxf(fmaf(b2f(zq[i]), scq[i], shq[i]), 0.f);
        acc = fmaf(x, wq[i], acc);
    }
#pragma unroll
    for (int off = 32; off; off >>= 1) acc += __shfl_down(acc, off, 64);
    if (lane == 0) out[pe[e]] = acc + b3[0] + bil[e];
}

extern "C" void kernel_launch(void* const* d_in, const int* in_sizes, int n_in,
                              void* d_out, int out_size, void* d_ws, size_t ws_size,
                              hipStream_t stream)
{
    const float* x_drug = (const float*)d_in[0];
    const float* x_prot = (const float*)d_in[1];
    const int*   ei     = (const int*)d_in[2];
    const float* W_src  = (const float*)d_in[3];
    const float* W_dst  = (const float*)d_in[4];
    const float* W_gate = (const float*)d_in[5];
    const float* b_gate = (const float*)d_in[6];
    const float* W1     = (const float*)d_in[7];
    const float* g1     = (const float*)d_in[9];
    const float* be1    = (const float*)d_in[10];
    const float* W2     = (const float*)d_in[11];
    const float* g2     = (const float*)d_in[13];
    const float* be2    = (const float*)d_in[14];
    const float* W3     = (const float*)d_in[15];
    const float* b3     = (const float*)d_in[16];
    const float* W_bil  = (const float*)d_in[17];
    const float* b_bil  = (const float*)d_in[18];
    float* out = (float*)d_out;

    const int N = in_sizes[0] / 256;   // 20000
    const int E = in_sizes[2] / 2;     // 300000

    char* wp_ = (char*)d_ws;
    auto alloc = [&](size_t bytes) {
        char* p = wp_; wp_ += (bytes + 255) & ~(size_t)255; return p;
    };
    u16* Wsrcb  = (u16*)alloc(256 * 256 * 2);
    u16* Wdstb  = (u16*)alloc(256 * 512 * 2);
    u16* Wgateb = (u16*)alloc(512 * 512 * 2);
    u16* Wbilb  = (u16*)alloc(256 * 256 * 2);
    u16* W1s    = (u16*)alloc(256 * 512 * 2);   // slab-major swizzled
    u16* W2s    = (u16*)alloc(256 * 256 * 2);   // slab-major swizzled
    u16* Hs     = (u16*)alloc((size_t)N * 256 * 2);
    u16* Hd     = (u16*)alloc((size_t)N * 256 * 2);
    u16* Gs     = (u16*)alloc((size_t)N * 512 * 2);
    u16* Gd     = (u16*)alloc((size_t)N * 512 * 2);
    u16* Bd     = (u16*)alloc((size_t)N * 256 * 2);
    u16* z      = (u16*)alloc((size_t)E * 256 * 2);   // z1, then z2 in-place
    float* bil  = (float*)alloc((size_t)E * 4);
    u32*  hist  = (u32*)alloc((size_t)N * 4);
    u32*  cursor= (u32*)alloc((size_t)N * 4);
    int2* sd    = (int2*)alloc((size_t)E * 8);
    int*  pe    = (int*)alloc((size_t)E * 4);
    float* sums   = (float*)alloc(1024 * 4);
    float* scale1 = (float*)alloc(256 * 4);
    float* shift1 = (float*)alloc(256 * 4);
    float* scale2 = (float*)alloc(256 * 4);
    float* shift2 = (float*)alloc(256 * 4);

    hipMemsetAsync(sums, 0, 1024 * 4, stream);
    hipMemsetAsync(hist, 0, (size_t)N * 4, stream);

    // edge sort by d
    hist_kernel<<<(E + 255) / 256, 256, 0, stream>>>(ei, E, hist);
    scan_kernel<<<1, 256, 0, stream>>>(hist, cursor, N);
    scatter_kernel<<<(E + 255) / 256, 256, 0, stream>>>(ei, E, cursor, sd, pe);

    CvtArr ca;
    ca.s[0] = {W_src,  Wsrcb,  256 * 256 / 4};
    ca.s[1] = {W_dst,  Wdstb,  256 * 512 / 4};
    ca.s[2] = {W_gate, Wgateb, 512 * 512 / 4};
    ca.s[3] = {W_bil,  Wbilb,  256 * 256 / 4};
    ca.tot4 = 0;
    for (int q = 0; q < 4; ++q) ca.tot4 += ca.s[q].n4;
    cvt_fused<<<(ca.tot4 + 255) / 256, 256, 0, stream>>>(ca);

    repack_swz<<<(256 * 512 + 255) / 256, 256, 0, stream>>>(W1, W1s, 256 * 512, 9);
    repack_swz<<<(256 * 256 + 255) / 256, 256, 0, stream>>>(W2, W2s, 256 * 256, 8);

    const int gxN = (N + 127) / 128;   // 157
    const int gxE = (E + 63) / 64;     // 4688

    GDescArr<2> p1;
    p1.d[0] = {x_drug, 256, 1, Wsrcb, 256, Hs, 256, 256, nullptr};
    p1.d[1] = {x_prot, 512, 1, Wdstb, 512, Hd, 256, 512, nullptr};
    mfma_node<2><<<dim3(gxN, 2), 256, 0, stream>>>(p1, N);

    GDescArr<5> p2;
    p2.d[0] = {Hs, 256, 0, Wgateb,                 512, Gs,       512, 256, b_gate};
    p2.d[1] = {Hs, 256, 0, Wgateb + 256 * 512,     512, Gs + 256, 512, 256, b_gate + 256};
    p2.d[2] = {Hd, 256, 0, Wgateb + 256,           512, Gd,       512, 256, nullptr};
    p2.d[3] = {Hd, 256, 0, Wgateb + 256 * 512 + 256, 512, Gd + 256, 512, 256, nullptr};
    p2.d[4] = {Hd, 256, 0, Wbilb,                  256, Bd,       256, 256, nullptr};
    mfma_node<5><<<dim3(gxN, 5), 256, 0, stream>>>(p2, N);

    // z1 = gated h @ W1.T + stats1 + fused bilinear (sorted edge order)
    mfma_edge<OP_GATE><<<gxE, 512, 0, stream>>>(
        nullptr, W1s, 512, z, E,
        sd, Gs, Gd, Hs, Hd, Bd, b_bil, bil, nullptr, nullptr, sums);
    finalize_kernel<<<1, 256, 0, stream>>>(sums, g1, be1, E, scale1, shift1);

    // z2 = relu(bn(z1)) @ W2.T  (in-place) + stats2
    mfma_edge<OP_BNRELU><<<gxE, 512, 0, stream>>>(
        z, W2s, 256, z, E,
        nullptr, nullptr, nullptr, nullptr, nullptr, nullptr, nullptr, nullptr,
        scale1, shift1, sums + 512);
    finalize_kernel<<<1, 256, 0, stream>>>(sums + 512, g2, be2, E, scale2, shift2);

    final_kernel<<<(E + 3) / 4, 256, 0, stream>>>(
        z, scale2, shift2, W3, b3, bil, pe, out, E);
}

// Round 16
// 584.021 us; speedup vs baseline: 1.0205x; 1.0039x over previous
//
#include <hip/hip_runtime.h>
#include <hip/hip_bf16.h>

typedef unsigned short u16;
typedef unsigned int u32;
typedef __attribute__((ext_vector_type(8))) short bf16x8;     // MFMA A/B frag (8 bf16)
typedef __attribute__((ext_vector_type(8))) unsigned short us8;
typedef __attribute__((ext_vector_type(4))) float f32x4;      // MFMA C/D frag

// ---------------------------------------------------------------------------
// Pipeline (v12 = r11-verified base + LDS-staged coalesced C-writes):
//   node GEMMs -> Hs,Hd,Gs,Gd,Bd (bf16, 72MB)
//   counting-sort edges by d (sd=int2 pairs, pe=orig index)
//   z1 = (sigmoid(Gs[s]+Gd[d]) * [Hs[s],Hd[d]]) @ W1.T + stats + fused bilinear
//   z2 = relu(bn(z1)) @ W2.T  in-place + stats
//   out[pe[i]] = dot(relu(bn(z2[i])),W3) + b3 + bil[i]
// Edge GEMM (r11): 64x256 tile, BK=64, 4 waves of 64x64; B via global_load_lds
// from pre-swizzled slab-major weights; A reg-staged (rcp gate), T14.
// v12 FIX: per-lane 2B C-stores covered only half a 64B line -> write-allocate
// RMW re-fetched the whole 150MB z stream from HBM (z1 FETCH 232MB vs 72MB
// node data). Now the C-tile is staged into Bs (dead after last MFMA, exact
// 32KB fit) and written as 16B/lane full-line coalesced stores.
// ---------------------------------------------------------------------------

__device__ __forceinline__ float b2f(u16 u) {
    union { unsigned u32v; float f; } x; x.u32v = ((unsigned)u) << 16; return x.f;
}
__device__ __forceinline__ u16 f2b(float f) {
    __hip_bfloat16 h = __float2bfloat16(f);
    u16 r; __builtin_memcpy(&r, &h, 2); return r;
}

struct CvtSeg { const float* in; u16* out; int n4; };
struct CvtArr { CvtSeg s[4]; int tot4; };
__global__ __launch_bounds__(256) void cvt_fused(CvtArr ca) {
    int i = blockIdx.x * 256 + threadIdx.x;
    if (i >= ca.tot4) return;
    int k = 0, off = i;
#pragma unroll
    for (int q = 0; q < 4; ++q) {
        if (off < ca.s[q].n4) { k = q; break; }
        off -= ca.s[q].n4;
    }
    float4 v = ((const float4*)ca.s[k].in)[off];
    ushort4 o; o.x = f2b(v.x); o.y = f2b(v.y); o.z = f2b(v.z); o.w = f2b(v.w);
    ((ushort4*)ca.s[k].out)[off] = o;
}

// repack W [256][K] f32 -> slab-major swizzled bf16 [K/64][256][64]
__global__ __launch_bounds__(256) void repack_swz(const float* __restrict__ W,
                                                  u16* __restrict__ out,
                                                  int total, int kbits) {
    int idx = blockIdx.x * 256 + threadIdx.x;
    if (idx >= total) return;
    const int n = idx >> kbits;
    const int k = idx & ((1 << kbits) - 1);
    const int ks = k >> 6, ke = k & 63;
    const int j = ke ^ ((n & 7) << 3);
    out[(((ks << 8) + n) << 6) + j] = f2b(W[idx]);
}

// ------------------------- edge sort by dst ---------------------------------
__global__ __launch_bounds__(256) void hist_kernel(const int* __restrict__ ei,
                                                   int E, u32* __restrict__ hist) {
    int e = blockIdx.x * 256 + threadIdx.x;
    if (e < E) atomicAdd(&hist[ei[E + e]], 1u);
}

__global__ __launch_bounds__(256) void scan_kernel(const u32* __restrict__ hist,
                                                   u32* __restrict__ cursor, int n) {
    __shared__ u32 part[256];
    const int t = threadIdx.x;
    const int chunk = (n + 255) / 256;
    const int lo = t * chunk, hi = min(lo + chunk, n);
    u32 s = 0;
    for (int i = lo; i < hi; ++i) s += hist[i];
    part[t] = s;
    __syncthreads();
    for (int off = 1; off < 256; off <<= 1) {
        u32 v = (t >= off) ? part[t - off] : 0u;
        __syncthreads();
        part[t] += v;
        __syncthreads();
    }
    u32 base = (t == 0) ? 0u : part[t - 1];
    for (int i = lo; i < hi; ++i) {
        cursor[i] = base;
        base += hist[i];
    }
}

__global__ __launch_bounds__(256) void scatter_kernel(const int* __restrict__ ei,
                                                      int E, u32* __restrict__ cursor,
                                                      int2* __restrict__ sd,
                                                      int* __restrict__ pe) {
    int e = blockIdx.x * 256 + threadIdx.x;
    if (e >= E) return;
    const int d = ei[E + e];
    const u32 pos = atomicAdd(&cursor[d], 1u);
    sd[pos] = make_int2(ei[e], d);
    pe[pos] = e;
}

// ------------------------- node GEMMs (desc-driven) -------------------------
struct GDesc {
    const void* A; int lda; int a_f32;
    const u16* W; int ldb;
    u16* C; int ldc;
    int K;
    const float* bias;
};
template <int NY> struct GDescArr { GDesc d[NY]; };

template <int NY>
__global__ __launch_bounds__(256, 2) void mfma_node(GDescArr<NY> da, int M)
{
    const GDesc dd = da.d[blockIdx.y];
    __shared__ u16 As[2][128][40];
    __shared__ u16 Bs[2][256][40];
    const int t = threadIdx.x;
    const int row0 = blockIdx.x * 128;
    const int arow = t >> 1, aks = (t & 1) * 16;
    const int agr = min(row0 + arow, M - 1);
    const int w = t >> 6, lane = t & 63;
    const int wr = w >> 1, wc = w & 1;
    const int lrow = lane & 15, lkg = lane >> 4;
    const int NIT = dd.K >> 5;

    f32x4 acc[4][8] = {};
    us8 ar[2], br[4];
    float4 fr[4];

    auto load_regs = [&](int it) {
        const int k0 = it << 5;
        if (dd.a_f32) {
            const float* ap = (const float*)dd.A + (size_t)agr * dd.lda + k0 + aks;
#pragma unroll
            for (int q = 0; q < 4; ++q) fr[q] = *(const float4*)(ap + q * 4);
        } else {
            const u16* ap = (const u16*)dd.A + (size_t)agr * dd.lda + k0 + aks;
            ar[0] = *(const us8*)ap; ar[1] = *(const us8*)(ap + 8);
        }
        const u16* wp = dd.W + (size_t)t * dd.ldb + k0;
#pragma unroll
        for (int q = 0; q < 4; ++q) br[q] = *(const us8*)(wp + q * 8);
    };
    auto proc_write = [&](int b) {
        if (dd.a_f32) {
#pragma unroll
            for (int q = 0; q < 2; ++q) {
                us8 o;
                const float fq[8] = {fr[q*2].x, fr[q*2].y, fr[q*2].z, fr[q*2].w,
                                     fr[q*2+1].x, fr[q*2+1].y, fr[q*2+1].z, fr[q*2+1].w};
#pragma unroll
                for (int j = 0; j < 8; ++j) o[j] = f2b(fq[j]);
                *(us8*)&As[b][arow][aks + q * 8] = o;
            }
        } else {
            *(us8*)&As[b][arow][aks] = ar[0];
            *(us8*)&As[b][arow][aks + 8] = ar[1];
        }
#pragma unroll
        for (int q = 0; q < 4; ++q) *(us8*)&Bs[b][t][q * 8] = br[q];
    };
    auto do_mfma = [&](int b) {
        bf16x8 af[4];
#pragma unroll
        for (int mi = 0; mi < 4; ++mi)
            af[mi] = *(const bf16x8*)&As[b][wr * 64 + mi * 16 + lrow][lkg * 8];
#pragma unroll
        for (int ni = 0; ni < 8; ++ni) {
            bf16x8 bfr = *(const bf16x8*)&Bs[b][wc * 128 + ni * 16 + lrow][lkg * 8];
#pragma unroll
            for (int mi = 0; mi < 4; ++mi)
                acc[mi][ni] = __builtin_amdgcn_mfma_f32_16x16x32_bf16(
                    af[mi], bfr, acc[mi][ni], 0, 0, 0);
        }
    };

    load_regs(0); proc_write(0); __syncthreads();
    for (int it = 0; it < NIT; ++it) {
        const int cur = it & 1;
        if (it + 1 < NIT) load_regs(it + 1);
        do_mfma(cur);
        if (it + 1 < NIT) proc_write(cur ^ 1);
        __syncthreads();
    }

#pragma unroll
    for (int ni = 0; ni < 8; ++ni) {
        const int gcol = wc * 128 + ni * 16 + lrow;
        const float bv = dd.bias ? dd.bias[gcol] : 0.f;
#pragma unroll
        for (int mi = 0; mi < 4; ++mi) {
            f32x4 v = acc[mi][ni];
#pragma unroll
            for (int j = 0; j < 4; ++j) {
                const int grow = row0 + wr * 64 + mi * 16 + lkg * 4 + j;
                if (grow < M) dd.C[(size_t)grow * dd.ldc + gcol] = f2b(v[j] + bv);
            }
        }
    }
}

// ------------------------- edge GEMMs (z1 / z2) -----------------------------
#define OP_GATE   1
#define OP_BNRELU 2

template <int AOP>
__global__ __launch_bounds__(256) void mfma_edge(
    const u16* __restrict__ Ain,            // z (BNRELU)
    const u16* __restrict__ Wb, int K,      // slab-major swizzled [K/64][256][64]
    u16* __restrict__ C, int E,
    const int2* __restrict__ sd,            // sorted (s,d) pairs
    const u16* __restrict__ Gs, const u16* __restrict__ Gd,
    const u16* __restrict__ Hs, const u16* __restrict__ Hd,
    const u16* __restrict__ Bd, const float* __restrict__ b_bil,
    float* __restrict__ bil,
    const float* __restrict__ scaleK, const float* __restrict__ shiftK,
    float* __restrict__ sums)
{
    __shared__ u16 As[64][72];        // padded: <=2-way banks on ds_read
    __shared__ u16 Bs[256 * 64];      // LINEAR (gload_lds dest); C-stage after loop
    __shared__ float wsum[2][256];

    const int t = threadIdx.x;
    const int row0 = blockIdx.x * 64;
    const int arow = t >> 2;          // 0..63 staged row (4 thr/row)
    const int aks  = (t & 3) * 16;    // k-offset within 64-slab
    const int agr = min(row0 + arow, E - 1);

    int s_ = 0, d_ = 0;
    if constexpr (AOP == OP_GATE) {
        int2 p = sd[agr]; s_ = p.x; d_ = p.y;
    }

    const int lane = t & 63;
    const int w = t >> 6;             // wave -> cols [w*64, w*64+64)
    const int lrow = lane & 15, lkg = lane >> 4;
    const int NKS = K >> 6;

    f32x4 acc[4][4] = {};
    float bdot = 0.f;
    us8 aw0, aw1;

    auto loadA = [&](int ks) {
        const int k = ks * 64 + aks;
        if constexpr (AOP == OP_GATE) {
            us8 gs0 = *(const us8*)(Gs + (size_t)s_ * 512 + k);
            us8 gs1 = *(const us8*)(Gs + (size_t)s_ * 512 + k + 8);
            us8 gd0 = *(const us8*)(Gd + (size_t)d_ * 512 + k);
            us8 gd1 = *(const us8*)(Gd + (size_t)d_ * 512 + k + 8);
            const u16* hp = (ks < 4) ? (Hs + (size_t)s_ * 256 + k)
                                     : (Hd + (size_t)d_ * 256 + k - 256);
            us8 h0 = *(const us8*)hp, h1 = *(const us8*)(hp + 8);
#pragma unroll
            for (int j = 0; j < 8; ++j) {
                const float x0 = b2f(gs0[j]) + b2f(gd0[j]);
                const float x1 = b2f(gs1[j]) + b2f(gd1[j]);
                const float r0 = __builtin_amdgcn_rcpf(1.f + __expf(-x0));
                const float r1 = __builtin_amdgcn_rcpf(1.f + __expf(-x1));
                aw0[j] = f2b(b2f(h0[j]) * r0);
                aw1[j] = f2b(b2f(h1[j]) * r1);
            }
            if (ks < 4) {
                us8 bd0 = *(const us8*)(Bd + (size_t)d_ * 256 + k);
                us8 bd1 = *(const us8*)(Bd + (size_t)d_ * 256 + k + 8);
#pragma unroll
                for (int j = 0; j < 8; ++j) {
                    bdot = fmaf(b2f(h0[j]), b2f(bd0[j]), bdot);
                    bdot = fmaf(b2f(h1[j]), b2f(bd1[j]), bdot);
                }
            }
        } else {
            us8 a0 = *(const us8*)(Ain + (size_t)agr * 256 + k);
            us8 a1 = *(const us8*)(Ain + (size_t)agr * 256 + k + 8);
            float4 c0 = *(const float4*)(scaleK + k);
            float4 c1 = *(const float4*)(scaleK + k + 4);
            float4 c2 = *(const float4*)(scaleK + k + 8);
            float4 c3 = *(const float4*)(scaleK + k + 12);
            float4 h0 = *(const float4*)(shiftK + k);
            float4 h1 = *(const float4*)(shiftK + k + 4);
            float4 h2 = *(const float4*)(shiftK + k + 8);
            float4 h3 = *(const float4*)(shiftK + k + 12);
            const float scq[16] = {c0.x,c0.y,c0.z,c0.w, c1.x,c1.y,c1.z,c1.w,
                                   c2.x,c2.y,c2.z,c2.w, c3.x,c3.y,c3.z,c3.w};
            const float shq[16] = {h0.x,h0.y,h0.z,h0.w, h1.x,h1.y,h1.z,h1.w,
                                   h2.x,h2.y,h2.z,h2.w, h3.x,h3.y,h3.z,h3.w};
#pragma unroll
            for (int j = 0; j < 8; ++j) {
                aw0[j] = f2b(fmaxf(fmaf(b2f(a0[j]), scq[j],     shq[j]),     0.f));
                aw1[j] = f2b(fmaxf(fmaf(b2f(a1[j]), scq[8 + j], shq[8 + j]), 0.f));
            }
        }
    };
    auto writeA = [&]() {
        *(us8*)&As[arow][aks]     = aw0;
        *(us8*)&As[arow][aks + 8] = aw1;
    };
    auto gloadB = [&](int ks) {
        const char* g = (const char*)(Wb + ((size_t)ks << 14)) + w * 8192 + lane * 16;
        char* l = (char*)Bs + w * 8192;
#pragma unroll
        for (int q = 0; q < 8; ++q)
            __builtin_amdgcn_global_load_lds(
                (const __attribute__((address_space(1))) unsigned int*)(g + q * 1024),
                (__attribute__((address_space(3))) unsigned int*)(l + q * 1024),
                16, 0, 0);
    };
    auto mfma_slab = [&]() {
#pragma unroll
        for (int kk = 0; kk < 64; kk += 32) {
            bf16x8 af[4], bf[4];
#pragma unroll
            for (int mi = 0; mi < 4; ++mi)
                af[mi] = *(const bf16x8*)&As[mi * 16 + lrow][kk + lkg * 8];
#pragma unroll
            for (int ni = 0; ni < 4; ++ni) {
                const int r = w * 64 + ni * 16 + lrow;
                bf[ni] = *(const bf16x8*)&Bs[r * 64 + ((kk + lkg * 8) ^ ((r & 7) << 3))];
            }
#pragma unroll
            for (int ni = 0; ni < 4; ++ni)
#pragma unroll
                for (int mi = 0; mi < 4; ++mi)
                    acc[mi][ni] = __builtin_amdgcn_mfma_f32_16x16x32_bf16(
                        af[mi], bf[ni], acc[mi][ni], 0, 0, 0);
        }
    };

    gloadB(0); loadA(0);
    for (int ks = 0; ks < NKS; ++ks) {
        writeA();
        __syncthreads();                  // As visible + B DMA drained
        if (ks + 1 < NKS) loadA(ks + 1);  // T14: gathers+gate overlap MFMA
        mfma_slab();
        __syncthreads();                  // Bs fully consumed
        if (ks + 1 < NKS) gloadB(ks + 1); // next slab DMA in flight
    }

    if constexpr (AOP == OP_GATE) {
        bdot += __shfl_xor(bdot, 1, 64);
        bdot += __shfl_xor(bdot, 2, 64);
        if ((t & 3) == 0 && row0 + arow < E)
            bil[row0 + arow] = bdot + b_bil[0];
    }

    // ---- epilogue v12: stage C tile into Bs (dead after last MFMA; last
    // barrier of the loop guarantees all waves are done reading it), then
    // write full 64B lines. Stats from registers as before. ----
    u16* Cs = Bs;                     // 64 x 256 u16 = 32KB, exact fit
#pragma unroll
    for (int ni = 0; ni < 4; ++ni) {
        const int gcol = w * 64 + ni * 16 + lrow;
        float s = 0.f, ss = 0.f;
#pragma unroll
        for (int mi = 0; mi < 4; ++mi) {
            f32x4 v = acc[mi][ni];
#pragma unroll
            for (int j = 0; j < 4; ++j) {
                const int lr_ = mi * 16 + lkg * 4 + j;      // local row 0..63
                const float x = v[j];
                Cs[lr_ * 256 + gcol] = f2b(x);
                if (row0 + lr_ < E) { s += x; ss = fmaf(x, x, ss); }
            }
        }
        s  += __shfl_xor(s, 16, 64);  s  += __shfl_xor(s, 32, 64);
        ss += __shfl_xor(ss, 16, 64); ss += __shfl_xor(ss, 32, 64);
        if (lkg == 0) { wsum[0][gcol] = s; wsum[1][gcol] = ss; }
    }
    __syncthreads();                  // Cs + wsum complete
    {
        const int limit = min(64, E - row0);   // valid rows in this tile
#pragma unroll
        for (int sw = 0; sw < 8; ++sw) {
            const int idx = sw * 2048 + t * 8;  // u16 index into 64x256 tile
            const int r = idx >> 8;
            if (r < limit)
                *(us8*)&C[(size_t)(row0 + r) * 256 + (idx & 255)] =
                    *(const us8*)&Cs[idx];
        }
    }
    atomicAdd(&sums[t],       wsum[0][t]);
    atomicAdd(&sums[256 + t], wsum[1][t]);
}

__global__ void finalize_kernel(
    const float* __restrict__ sums, const float* __restrict__ g,
    const float* __restrict__ be, int M,
    float* __restrict__ scale, float* __restrict__ shift)
{
    const int c = threadIdx.x;
    const float inv = 1.f / (float)M;
    const float mean = sums[c] * inv;
    const float var  = sums[256 + c] * inv - mean * mean;
    const float sc = g[c] * rsqrtf(var + 1e-5f);
    scale[c] = sc;
    shift[c] = fmaf(-mean, sc, be[c]);
}

// out[pe[i]] = dot(relu(bn(z2[i])),W3)+b3 + bil[i]   (one wave / sorted edge)
__global__ __launch_bounds__(256) void final_kernel(
    const u16* __restrict__ Z2,
    const float* __restrict__ scale2, const float* __restrict__ shift2,
    const float* __restrict__ W3, const float* __restrict__ b3,
    const float* __restrict__ bil, const int* __restrict__ pe,
    float* __restrict__ out, int E)
{
    const int w = threadIdx.x >> 6, lane = threadIdx.x & 63;
    const int e = blockIdx.x * 4 + w;
    if (e >= E) return;
    ushort4 zv = *(const ushort4*)(Z2 + (size_t)e * 256 + lane * 4);
    float4 sc = *(const float4*)(scale2 + lane * 4);
    float4 sh = *(const float4*)(shift2 + lane * 4);
    float4 w3 = *(const float4*)(W3 + lane * 4);
    const u16 zq[4] = {zv.x, zv.y, zv.z, zv.w};
    const float scq[4] = {sc.x, sc.y, sc.z, sc.w};
    const float shq[4] = {sh.x, sh.y, sh.z, sh.w};
    const float wq[4] = {w3.x, w3.y, w3.z, w3.w};
    float acc = 0.f;
#pragma unroll
    for (int i = 0; i < 4; ++i) {
        const float x = fmaxf(fmaf(b2f(zq[i]), scq[i], shq[i]), 0.f);
        acc = fmaf(x, wq[i], acc);
    }
#pragma unroll
    for (int off = 32; off; off >>= 1) acc += __shfl_down(acc, off, 64);
    if (lane == 0) out[pe[e]] = acc + b3[0] + bil[e];
}

extern "C" void kernel_launch(void* const* d_in, const int* in_sizes, int n_in,
                              void* d_out, int out_size, void* d_ws, size_t ws_size,
                              hipStream_t stream)
{
    const float* x_drug = (const float*)d_in[0];
    const float* x_prot = (const float*)d_in[1];
    const int*   ei     = (const int*)d_in[2];
    const float* W_src  = (const float*)d_in[3];
    const float* W_dst  = (const float*)d_in[4];
    const float* W_gate = (const float*)d_in[5];
    const float* b_gate = (const float*)d_in[6];
    const float* W1     = (const float*)d_in[7];
    const float* g1     = (const float*)d_in[9];
    const float* be1    = (const float*)d_in[10];
    const float* W2     = (const float*)d_in[11];
    const float* g2     = (const float*)d_in[13];
    const float* be2    = (const float*)d_in[14];
    const float* W3     = (const float*)d_in[15];
    const float* b3     = (const float*)d_in[16];
    const float* W_bil  = (const float*)d_in[17];
    const float* b_bil  = (const float*)d_in[18];
    float* out = (float*)d_out;

    const int N = in_sizes[0] / 256;   // 20000
    const int E = in_sizes[2] / 2;     // 300000

    char* wp_ = (char*)d_ws;
    auto alloc = [&](size_t bytes) {
        char* p = wp_; wp_ += (bytes + 255) & ~(size_t)255; return p;
    };
    u16* Wsrcb  = (u16*)alloc(256 * 256 * 2);
    u16* Wdstb  = (u16*)alloc(256 * 512 * 2);
    u16* Wgateb = (u16*)alloc(512 * 512 * 2);
    u16* Wbilb  = (u16*)alloc(256 * 256 * 2);
    u16* W1s    = (u16*)alloc(256 * 512 * 2);   // slab-major swizzled
    u16* W2s    = (u16*)alloc(256 * 256 * 2);   // slab-major swizzled
    u16* Hs     = (u16*)alloc((size_t)N * 256 * 2);
    u16* Hd     = (u16*)alloc((size_t)N * 256 * 2);
    u16* Gs     = (u16*)alloc((size_t)N * 512 * 2);
    u16* Gd     = (u16*)alloc((size_t)N * 512 * 2);
    u16* Bd     = (u16*)alloc((size_t)N * 256 * 2);
    u16* z      = (u16*)alloc((size_t)E * 256 * 2);   // z1, then z2 in-place
    float* bil  = (float*)alloc((size_t)E * 4);
    u32*  hist  = (u32*)alloc((size_t)N * 4);
    u32*  cursor= (u32*)alloc((size_t)N * 4);
    int2* sd    = (int2*)alloc((size_t)E * 8);
    int*  pe    = (int*)alloc((size_t)E * 4);
    float* sums   = (float*)alloc(1024 * 4);
    float* scale1 = (float*)alloc(256 * 4);
    float* shift1 = (float*)alloc(256 * 4);
    float* scale2 = (float*)alloc(256 * 4);
    float* shift2 = (float*)alloc(256 * 4);

    hipMemsetAsync(sums, 0, 1024 * 4, stream);
    hipMemsetAsync(hist, 0, (size_t)N * 4, stream);

    // edge sort by d
    hist_kernel<<<(E + 255) / 256, 256, 0, stream>>>(ei, E, hist);
    scan_kernel<<<1, 256, 0, stream>>>(hist, cursor, N);
    scatter_kernel<<<(E + 255) / 256, 256, 0, stream>>>(ei, E, cursor, sd, pe);

    CvtArr ca;
    ca.s[0] = {W_src,  Wsrcb,  256 * 256 / 4};
    ca.s[1] = {W_dst,  Wdstb,  256 * 512 / 4};
    ca.s[2] = {W_gate, Wgateb, 512 * 512 / 4};
    ca.s[3] = {W_bil,  Wbilb,  256 * 256 / 4};
    ca.tot4 = 0;
    for (int q = 0; q < 4; ++q) ca.tot4 += ca.s[q].n4;
    cvt_fused<<<(ca.tot4 + 255) / 256, 256, 0, stream>>>(ca);

    repack_swz<<<(256 * 512 + 255) / 256, 256, 0, stream>>>(W1, W1s, 256 * 512, 9);
    repack_swz<<<(256 * 256 + 255) / 256, 256, 0, stream>>>(W2, W2s, 256 * 256, 8);

    const int gxN = (N + 127) / 128;   // 157
    const int gxE = (E + 63) / 64;     // 4688

    GDescArr<2> p1;
    p1.d[0] = {x_drug, 256, 1, Wsrcb, 256, Hs, 256, 256, nullptr};
    p1.d[1] = {x_prot, 512, 1, Wdstb, 512, Hd, 256, 512, nullptr};
    mfma_node<2><<<dim3(gxN, 2), 256, 0, stream>>>(p1, N);

    GDescArr<5> p2;
    p2.d[0] = {Hs, 256, 0, Wgateb,                 512, Gs,       512, 256, b_gate};
    p2.d[1] = {Hs, 256, 0, Wgateb + 256 * 512,     512, Gs + 256, 512, 256, b_gate + 256};
    p2.d[2] = {Hd, 256, 0, Wgateb + 256,           512, Gd,       512, 256, nullptr};
    p2.d[3] = {Hd, 256, 0, Wgateb + 256 * 512 + 256, 512, Gd + 256, 512, 256, nullptr};
    p2.d[4] = {Hd, 256, 0, Wbilb,                  256, Bd,       256, 256, nullptr};
    mfma_node<5><<<dim3(gxN, 5), 256, 0, stream>>>(p2, N);

    // z1 = gated h @ W1.T + stats1 + fused bilinear (sorted edge order)
    mfma_edge<OP_GATE><<<gxE, 256, 0, stream>>>(
        nullptr, W1s, 512, z, E,
        sd, Gs, Gd, Hs, Hd, Bd, b_bil, bil, nullptr, nullptr, sums);
    finalize_kernel<<<1, 256, 0, stream>>>(sums, g1, be1, E, scale1, shift1);

    // z2 = relu(bn(z1)) @ W2.T  (in-place) + stats2
    mfma_edge<OP_BNRELU><<<gxE, 256, 0, stream>>>(
        z, W2s, 256, z, E,
        nullptr, nullptr, nullptr, nullptr, nullptr, nullptr, nullptr, nullptr,
        scale1, shift1, sums + 512);
    finalize_kernel<<<1, 256, 0, stream>>>(sums + 512, g2, be2, E, scale2, shift2);

    final_kernel<<<(E + 3) / 4, 256, 0, stream>>>(
        z, scale2, shift2, W3, b3, bil, pe, out, E);
}

// Round 17
// 520.944 us; speedup vs baseline: 1.1440x; 1.1211x over previous
//
#include <hip/hip_runtime.h>
#include <hip/hip_bf16.h>

typedef unsigned short u16;
typedef unsigned int u32;
typedef __attribute__((ext_vector_type(8))) short bf16x8;     // MFMA A/B frag (8 bf16)
typedef __attribute__((ext_vector_type(8))) unsigned short us8;
typedef __attribute__((ext_vector_type(4))) float f32x4;      // MFMA C/D frag

// ---------------------------------------------------------------------------
// Pipeline (v13 = round-9 structure [session best, 525.7us] + native bf16 cvt):
//   node GEMMs -> Hs,Hd,Gs,Gd,Bd (bf16, 72MB)
//   z1 = (sigmoid(Gs[s]+Gd[d]) * [Hs[s],Hd[d]]) @ W1.T + stats + fused bilinear
//   z2 = relu(bn(z1)) @ W2.T  in-place + stats
//   out = dot(relu(bn(z2)),W3) + b3 + bil     (original edge order; NO sort —
//   r10-r16 established the sort pipeline costs ~70us vs ~28us z1 savings)
// Edge GEMM (r9-proven): 64x256 tile, BK=64, 4 waves of 64x64; B via
// global_load_lds from pre-swizzled slab-major weights; A reg-staged
// (rcp gate), T14 issue-early.
// ---------------------------------------------------------------------------

__device__ __forceinline__ float b2f(u16 u) {
    union { unsigned u32v; float f; } x; x.u32v = ((unsigned)u) << 16; return x.f;
}
__device__ __forceinline__ u16 f2b(float f) {
    __hip_bfloat16 h = __float2bfloat16(f);
    u16 r; __builtin_memcpy(&r, &h, 2); return r;
}

struct CvtSeg { const float* in; u16* out; int n4; };
struct CvtArr { CvtSeg s[4]; int tot4; };
__global__ __launch_bounds__(256) void cvt_fused(CvtArr ca) {
    int i = blockIdx.x * 256 + threadIdx.x;
    if (i >= ca.tot4) return;
    int k = 0, off = i;
#pragma unroll
    for (int q = 0; q < 4; ++q) {
        if (off < ca.s[q].n4) { k = q; break; }
        off -= ca.s[q].n4;
    }
    float4 v = ((const float4*)ca.s[k].in)[off];
    ushort4 o; o.x = f2b(v.x); o.y = f2b(v.y); o.z = f2b(v.z); o.w = f2b(v.w);
    ((ushort4*)ca.s[k].out)[off] = o;
}

// repack W [256][K] f32 -> slab-major swizzled bf16 [K/64][256][64]
__global__ __launch_bounds__(256) void repack_swz(const float* __restrict__ W,
                                                  u16* __restrict__ out,
                                                  int total, int kbits) {
    int idx = blockIdx.x * 256 + threadIdx.x;
    if (idx >= total) return;
    const int n = idx >> kbits;
    const int k = idx & ((1 << kbits) - 1);
    const int ks = k >> 6, ke = k & 63;
    const int j = ke ^ ((n & 7) << 3);
    out[(((ks << 8) + n) << 6) + j] = f2b(W[idx]);
}

// ------------------------- node GEMMs (desc-driven) -------------------------
struct GDesc {
    const void* A; int lda; int a_f32;
    const u16* W; int ldb;
    u16* C; int ldc;
    int K;
    const float* bias;
};
template <int NY> struct GDescArr { GDesc d[NY]; };

template <int NY>
__global__ __launch_bounds__(256, 2) void mfma_node(GDescArr<NY> da, int M)
{
    const GDesc dd = da.d[blockIdx.y];
    __shared__ u16 As[2][128][40];
    __shared__ u16 Bs[2][256][40];
    const int t = threadIdx.x;
    const int row0 = blockIdx.x * 128;
    const int arow = t >> 1, aks = (t & 1) * 16;
    const int agr = min(row0 + arow, M - 1);
    const int w = t >> 6, lane = t & 63;
    const int wr = w >> 1, wc = w & 1;
    const int lrow = lane & 15, lkg = lane >> 4;
    const int NIT = dd.K >> 5;

    f32x4 acc[4][8] = {};
    us8 ar[2], br[4];
    float4 fr[4];

    auto load_regs = [&](int it) {
        const int k0 = it << 5;
        if (dd.a_f32) {
            const float* ap = (const float*)dd.A + (size_t)agr * dd.lda + k0 + aks;
#pragma unroll
            for (int q = 0; q < 4; ++q) fr[q] = *(const float4*)(ap + q * 4);
        } else {
            const u16* ap = (const u16*)dd.A + (size_t)agr * dd.lda + k0 + aks;
            ar[0] = *(const us8*)ap; ar[1] = *(const us8*)(ap + 8);
        }
        const u16* wp = dd.W + (size_t)t * dd.ldb + k0;
#pragma unroll
        for (int q = 0; q < 4; ++q) br[q] = *(const us8*)(wp + q * 8);
    };
    auto proc_write = [&](int b) {
        if (dd.a_f32) {
#pragma unroll
            for (int q = 0; q < 2; ++q) {
                us8 o;
                const float fq[8] = {fr[q*2].x, fr[q*2].y, fr[q*2].z, fr[q*2].w,
                                     fr[q*2+1].x, fr[q*2+1].y, fr[q*2+1].z, fr[q*2+1].w};
#pragma unroll
                for (int j = 0; j < 8; ++j) o[j] = f2b(fq[j]);
                *(us8*)&As[b][arow][aks + q * 8] = o;
            }
        } else {
            *(us8*)&As[b][arow][aks] = ar[0];
            *(us8*)&As[b][arow][aks + 8] = ar[1];
        }
#pragma unroll
        for (int q = 0; q < 4; ++q) *(us8*)&Bs[b][t][q * 8] = br[q];
    };
    auto do_mfma = [&](int b) {
        bf16x8 af[4];
#pragma unroll
        for (int mi = 0; mi < 4; ++mi)
            af[mi] = *(const bf16x8*)&As[b][wr * 64 + mi * 16 + lrow][lkg * 8];
#pragma unroll
        for (int ni = 0; ni < 8; ++ni) {
            bf16x8 bfr = *(const bf16x8*)&Bs[b][wc * 128 + ni * 16 + lrow][lkg * 8];
#pragma unroll
            for (int mi = 0; mi < 4; ++mi)
                acc[mi][ni] = __builtin_amdgcn_mfma_f32_16x16x32_bf16(
                    af[mi], bfr, acc[mi][ni], 0, 0, 0);
        }
    };

    load_regs(0); proc_write(0); __syncthreads();
    for (int it = 0; it < NIT; ++it) {
        const int cur = it & 1;
        if (it + 1 < NIT) load_regs(it + 1);
        do_mfma(cur);
        if (it + 1 < NIT) proc_write(cur ^ 1);
        __syncthreads();
    }

#pragma unroll
    for (int ni = 0; ni < 8; ++ni) {
        const int gcol = wc * 128 + ni * 16 + lrow;
        const float bv = dd.bias ? dd.bias[gcol] : 0.f;
#pragma unroll
        for (int mi = 0; mi < 4; ++mi) {
            f32x4 v = acc[mi][ni];
#pragma unroll
            for (int j = 0; j < 4; ++j) {
                const int grow = row0 + wr * 64 + mi * 16 + lkg * 4 + j;
                if (grow < M) dd.C[(size_t)grow * dd.ldc + gcol] = f2b(v[j] + bv);
            }
        }
    }
}

// ------------------------- edge GEMMs (z1 / z2) -----------------------------
#define OP_GATE   1
#define OP_BNRELU 2

template <int AOP>
__global__ __launch_bounds__(256) void mfma_edge(
    const u16* __restrict__ Ain,            // z (BNRELU)
    const u16* __restrict__ Wb, int K,      // slab-major swizzled [K/64][256][64]
    u16* __restrict__ C, int E,
    const int* __restrict__ ei,
    const u16* __restrict__ Gs, const u16* __restrict__ Gd,
    const u16* __restrict__ Hs, const u16* __restrict__ Hd,
    const u16* __restrict__ Bd, const float* __restrict__ b_bil,
    float* __restrict__ bil,
    const float* __restrict__ scaleK, const float* __restrict__ shiftK,
    float* __restrict__ sums)
{
    __shared__ u16 As[64][72];        // padded: <=2-way banks on ds_read
    __shared__ u16 Bs[256 * 64];      // LINEAR (gload_lds dest), swizzled content
    __shared__ float wsum[2][256];

    const int t = threadIdx.x;
    const int row0 = blockIdx.x * 64;
    const int arow = t >> 2;          // 0..63 staged row (4 thr/row)
    const int aks  = (t & 3) * 16;    // k-offset within 64-slab
    const int agr = min(row0 + arow, E - 1);

    int s_ = 0, d_ = 0;
    if constexpr (AOP == OP_GATE) { s_ = ei[agr]; d_ = ei[E + agr]; }

    const int lane = t & 63;
    const int w = t >> 6;             // wave -> cols [w*64, w*64+64)
    const int lrow = lane & 15, lkg = lane >> 4;
    const int NKS = K >> 6;

    f32x4 acc[4][4] = {};
    float bdot = 0.f;
    us8 aw0, aw1;

    auto loadA = [&](int ks) {
        const int k = ks * 64 + aks;
        if constexpr (AOP == OP_GATE) {
            us8 gs0 = *(const us8*)(Gs + (size_t)s_ * 512 + k);
            us8 gs1 = *(const us8*)(Gs + (size_t)s_ * 512 + k + 8);
            us8 gd0 = *(const us8*)(Gd + (size_t)d_ * 512 + k);
            us8 gd1 = *(const us8*)(Gd + (size_t)d_ * 512 + k + 8);
            const u16* hp = (ks < 4) ? (Hs + (size_t)s_ * 256 + k)
                                     : (Hd + (size_t)d_ * 256 + k - 256);
            us8 h0 = *(const us8*)hp, h1 = *(const us8*)(hp + 8);
#pragma unroll
            for (int j = 0; j < 8; ++j) {
                const float x0 = b2f(gs0[j]) + b2f(gd0[j]);
                const float x1 = b2f(gs1[j]) + b2f(gd1[j]);
                const float r0 = __builtin_amdgcn_rcpf(1.f + __expf(-x0));
                const float r1 = __builtin_amdgcn_rcpf(1.f + __expf(-x1));
                aw0[j] = f2b(b2f(h0[j]) * r0);
                aw1[j] = f2b(b2f(h1[j]) * r1);
            }
            if (ks < 4) {
                us8 bd0 = *(const us8*)(Bd + (size_t)d_ * 256 + k);
                us8 bd1 = *(const us8*)(Bd + (size_t)d_ * 256 + k + 8);
#pragma unroll
                for (int j = 0; j < 8; ++j) {
                    bdot = fmaf(b2f(h0[j]), b2f(bd0[j]), bdot);
                    bdot = fmaf(b2f(h1[j]), b2f(bd1[j]), bdot);
                }
            }
        } else {
            us8 a0 = *(const us8*)(Ain + (size_t)agr * 256 + k);
            us8 a1 = *(const us8*)(Ain + (size_t)agr * 256 + k + 8);
            float4 c0 = *(const float4*)(scaleK + k);
            float4 c1 = *(const float4*)(scaleK + k + 4);
            float4 c2 = *(const float4*)(scaleK + k + 8);
            float4 c3 = *(const float4*)(scaleK + k + 12);
            float4 h0 = *(const float4*)(shiftK + k);
            float4 h1 = *(const float4*)(shiftK + k + 4);
            float4 h2 = *(const float4*)(shiftK + k + 8);
            float4 h3 = *(const float4*)(shiftK + k + 12);
            const float scq[16] = {c0.x,c0.y,c0.z,c0.w, c1.x,c1.y,c1.z,c1.w,
                                   c2.x,c2.y,c2.z,c2.w, c3.x,c3.y,c3.z,c3.w};
            const float shq[16] = {h0.x,h0.y,h0.z,h0.w, h1.x,h1.y,h1.z,h1.w,
                                   h2.x,h2.y,h2.z,h2.w, h3.x,h3.y,h3.z,h3.w};
#pragma unroll
            for (int j = 0; j < 8; ++j) {
                aw0[j] = f2b(fmaxf(fmaf(b2f(a0[j]), scq[j],     shq[j]),     0.f));
                aw1[j] = f2b(fmaxf(fmaf(b2f(a1[j]), scq[8 + j], shq[8 + j]), 0.f));
            }
        }
    };
    auto writeA = [&]() {
        *(us8*)&As[arow][aks]     = aw0;
        *(us8*)&As[arow][aks + 8] = aw1;
    };
    auto gloadB = [&](int ks) {
        const char* g = (const char*)(Wb + ((size_t)ks << 14)) + w * 8192 + lane * 16;
        char* l = (char*)Bs + w * 8192;
#pragma unroll
        for (int q = 0; q < 8; ++q)
            __builtin_amdgcn_global_load_lds(
                (const __attribute__((address_space(1))) unsigned int*)(g + q * 1024),
                (__attribute__((address_space(3))) unsigned int*)(l + q * 1024),
                16, 0, 0);
    };
    auto mfma_slab = [&]() {
#pragma unroll
        for (int kk = 0; kk < 64; kk += 32) {
            bf16x8 af[4], bf[4];
#pragma unroll
            for (int mi = 0; mi < 4; ++mi)
                af[mi] = *(const bf16x8*)&As[mi * 16 + lrow][kk + lkg * 8];
#pragma unroll
            for (int ni = 0; ni < 4; ++ni) {
                const int r = w * 64 + ni * 16 + lrow;
                bf[ni] = *(const bf16x8*)&Bs[r * 64 + ((kk + lkg * 8) ^ ((r & 7) << 3))];
            }
#pragma unroll
            for (int ni = 0; ni < 4; ++ni)
#pragma unroll
                for (int mi = 0; mi < 4; ++mi)
                    acc[mi][ni] = __builtin_amdgcn_mfma_f32_16x16x32_bf16(
                        af[mi], bf[ni], acc[mi][ni], 0, 0, 0);
        }
    };

    gloadB(0); loadA(0);
    for (int ks = 0; ks < NKS; ++ks) {
        writeA();
        __syncthreads();                  // As visible + B DMA drained
        if (ks + 1 < NKS) loadA(ks + 1);  // T14: gathers+gate overlap MFMA
        mfma_slab();
        __syncthreads();                  // Bs fully consumed
        if (ks + 1 < NKS) gloadB(ks + 1); // next slab DMA in flight
    }

    if constexpr (AOP == OP_GATE) {
        bdot += __shfl_xor(bdot, 1, 64);
        bdot += __shfl_xor(bdot, 2, 64);
        if ((t & 3) == 0 && row0 + arow < E)
            bil[row0 + arow] = bdot + b_bil[0];
    }

    // epilogue: C-write + fused per-column stats
#pragma unroll
    for (int ni = 0; ni < 4; ++ni) {
        const int gcol = w * 64 + ni * 16 + lrow;
        float s = 0.f, ss = 0.f;
#pragma unroll
        for (int mi = 0; mi < 4; ++mi) {
            f32x4 v = acc[mi][ni];
#pragma unroll
            for (int j = 0; j < 4; ++j) {
                const int grow = row0 + mi * 16 + lkg * 4 + j;
                const float x = v[j];
                if (grow < E) {
                    C[(size_t)grow * 256 + gcol] = f2b(x);
                    s += x; ss = fmaf(x, x, ss);
                }
            }
        }
        s  += __shfl_xor(s, 16, 64);  s  += __shfl_xor(s, 32, 64);
        ss += __shfl_xor(ss, 16, 64); ss += __shfl_xor(ss, 32, 64);
        if (lkg == 0) { wsum[0][gcol] = s; wsum[1][gcol] = ss; }
    }
    __syncthreads();
    atomicAdd(&sums[t],       wsum[0][t]);
    atomicAdd(&sums[256 + t], wsum[1][t]);
}

__global__ void finalize_kernel(
    const float* __restrict__ sums, const float* __restrict__ g,
    const float* __restrict__ be, int M,
    float* __restrict__ scale, float* __restrict__ shift)
{
    const int c = threadIdx.x;
    const float inv = 1.f / (float)M;
    const float mean = sums[c] * inv;
    const float var  = sums[256 + c] * inv - mean * mean;
    const float sc = g[c] * rsqrtf(var + 1e-5f);
    scale[c] = sc;
    shift[c] = fmaf(-mean, sc, be[c]);
}

// out = dot(relu(bn(z2)),W3)+b3 + bil   (one wave / edge, original order)
__global__ __launch_bounds__(256) void final_kernel(
    const u16* __restrict__ Z2,
    const float* __restrict__ scale2, const float* __restrict__ shift2,
    const float* __restrict__ W3, const float* __restrict__ b3,
    const float* __restrict__ bil,
    float* __restrict__ out, int E)
{
    const int w = threadIdx.x >> 6, lane = threadIdx.x & 63;
    const int e = blockIdx.x * 4 + w;
    if (e >= E) return;
    ushort4 zv = *(const ushort4*)(Z2 + (size_t)e * 256 + lane * 4);
    float4 sc = *(const float4*)(scale2 + lane * 4);
    float4 sh = *(const float4*)(shift2 + lane * 4);
    float4 w3 = *(const float4*)(W3 + lane * 4);
    const u16 zq[4] = {zv.x, zv.y, zv.z, zv.w};
    const float scq[4] = {sc.x, sc.y, sc.z, sc.w};
    const float shq[4] = {sh.x, sh.y, sh.z, sh.w};
    const float wq[4] = {w3.x, w3.y, w3.z, w3.w};
    float acc = 0.f;
#pragma unroll
    for (int i = 0; i < 4; ++i) {
        const float x = fmaxf(fmaf(b2f(zq[i]), scq[i], shq[i]), 0.f);
        acc = fmaf(x, wq[i], acc);
    }
#pragma unroll
    for (int off = 32; off; off >>= 1) acc += __shfl_down(acc, off, 64);
    if (lane == 0) out[e] = acc + b3[0] + bil[e];
}

extern "C" void kernel_launch(void* const* d_in, const int* in_sizes, int n_in,
                              void* d_out, int out_size, void* d_ws, size_t ws_size,
                              hipStream_t stream)
{
    const float* x_drug = (const float*)d_in[0];
    const float* x_prot = (const float*)d_in[1];
    const int*   ei     = (const int*)d_in[2];
    const float* W_src  = (const float*)d_in[3];
    const float* W_dst  = (const float*)d_in[4];
    const float* W_gate = (const float*)d_in[5];
    const float* b_gate = (const float*)d_in[6];
    const float* W1     = (const float*)d_in[7];
    const float* g1     = (const float*)d_in[9];
    const float* be1    = (const float*)d_in[10];
    const float* W2     = (const float*)d_in[11];
    const float* g2     = (const float*)d_in[13];
    const float* be2    = (const float*)d_in[14];
    const float* W3     = (const float*)d_in[15];
    const float* b3     = (const float*)d_in[16];
    const float* W_bil  = (const float*)d_in[17];
    const float* b_bil  = (const float*)d_in[18];
    float* out = (float*)d_out;

    const int N = in_sizes[0] / 256;   // 20000
    const int E = in_sizes[2] / 2;     // 300000

    char* wp_ = (char*)d_ws;
    auto alloc = [&](size_t bytes) {
        char* p = wp_; wp_ += (bytes + 255) & ~(size_t)255; return p;
    };
    u16* Wsrcb  = (u16*)alloc(256 * 256 * 2);
    u16* Wdstb  = (u16*)alloc(256 * 512 * 2);
    u16* Wgateb = (u16*)alloc(512 * 512 * 2);
    u16* Wbilb  = (u16*)alloc(256 * 256 * 2);
    u16* W1s    = (u16*)alloc(256 * 512 * 2);   // slab-major swizzled
    u16* W2s    = (u16*)alloc(256 * 256 * 2);   // slab-major swizzled
    u16* Hs     = (u16*)alloc((size_t)N * 256 * 2);
    u16* Hd     = (u16*)alloc((size_t)N * 256 * 2);
    u16* Gs     = (u16*)alloc((size_t)N * 512 * 2);
    u16* Gd     = (u16*)alloc((size_t)N * 512 * 2);
    u16* Bd     = (u16*)alloc((size_t)N * 256 * 2);
    u16* z      = (u16*)alloc((size_t)E * 256 * 2);   // z1, then z2 in-place
    float* bil  = (float*)alloc((size_t)E * 4);
    float* sums   = (float*)alloc(1024 * 4);
    float* scale1 = (float*)alloc(256 * 4);
    float* shift1 = (float*)alloc(256 * 4);
    float* scale2 = (float*)alloc(256 * 4);
    float* shift2 = (float*)alloc(256 * 4);

    hipMemsetAsync(sums, 0, 1024 * 4, stream);

    CvtArr ca;
    ca.s[0] = {W_src,  Wsrcb,  256 * 256 / 4};
    ca.s[1] = {W_dst,  Wdstb,  256 * 512 / 4};
    ca.s[2] = {W_gate, Wgateb, 512 * 512 / 4};
    ca.s[3] = {W_bil,  Wbilb,  256 * 256 / 4};
    ca.tot4 = 0;
    for (int q = 0; q < 4; ++q) ca.tot4 += ca.s[q].n4;
    cvt_fused<<<(ca.tot4 + 255) / 256, 256, 0, stream>>>(ca);

    repack_swz<<<(256 * 512 + 255) / 256, 256, 0, stream>>>(W1, W1s, 256 * 512, 9);
    repack_swz<<<(256 * 256 + 255) / 256, 256, 0, stream>>>(W2, W2s, 256 * 256, 8);

    const int gxN = (N + 127) / 128;   // 157
    const int gxE = (E + 63) / 64;     // 4688

    GDescArr<2> p1;
    p1.d[0] = {x_drug, 256, 1, Wsrcb, 256, Hs, 256, 256, nullptr};
    p1.d[1] = {x_prot, 512, 1, Wdstb, 512, Hd, 256, 512, nullptr};
    mfma_node<2><<<dim3(gxN, 2), 256, 0, stream>>>(p1, N);

    GDescArr<5> p2;
    p2.d[0] = {Hs, 256, 0, Wgateb,                 512, Gs,       512, 256, b_gate};
    p2.d[1] = {Hs, 256, 0, Wgateb + 256 * 512,     512, Gs + 256, 512, 256, b_gate + 256};
    p2.d[2] = {Hd, 256, 0, Wgateb + 256,           512, Gd,       512, 256, nullptr};
    p2.d[3] = {Hd, 256, 0, Wgateb + 256 * 512 + 256, 512, Gd + 256, 512, 256, nullptr};
    p2.d[4] = {Hd, 256, 0, Wbilb,                  256, Bd,       256, 256, nullptr};
    mfma_node<5><<<dim3(gxN, 5), 256, 0, stream>>>(p2, N);

    // z1 = gated h @ W1.T + stats1 + fused bilinear
    mfma_edge<OP_GATE><<<gxE, 256, 0, stream>>>(
        nullptr, W1s, 512, z, E,
        ei, Gs, Gd, Hs, Hd, Bd, b_bil, bil, nullptr, nullptr, sums);
    finalize_kernel<<<1, 256, 0, stream>>>(sums, g1, be1, E, scale1, shift1);

    // z2 = relu(bn(z1)) @ W2.T  (in-place) + stats2
    mfma_edge<OP_BNRELU><<<gxE, 256, 0, stream>>>(
        z, W2s, 256, z, E,
        nullptr, nullptr, nullptr, nullptr, nullptr, nullptr, nullptr, nullptr,
        scale1, shift1, sums + 512);
    finalize_kernel<<<1, 256, 0, stream>>>(sums + 512, g2, be2, E, scale2, shift2);

    final_kernel<<<(E + 3) / 4, 256, 0, stream>>>(
        z, scale2, shift2, W3, b3, bil, out, E);
}